// Round 10
// baseline (641.230 us; speedup 1.0000x reference)
//
#include <hip/hip_runtime.h>
#include <hip/hip_bf16.h>

#define C_IN 256
#define C_HID 256
#define C_OUT 64
#define EPSV 1e-5f

// graph-prep histogram geometry
#define NCHUNK 16
#define NCHUNK_LOG 4
#define RANGE 3136           // 16*3136 = 50176 >= N
#define NPAD2 (NCHUNK * RANGE)
#define ECHUNK 64

typedef __bf16 bfv8 __attribute__((ext_vector_type(8)));
typedef float f32x4 __attribute__((ext_vector_type(4)));
typedef unsigned short ushort8v __attribute__((ext_vector_type(8)));

__device__ __forceinline__ float bf2f(unsigned short u) {
    return __uint_as_float(((unsigned int)u) << 16);
}
__device__ __forceinline__ unsigned short f2bf(float f) {
    unsigned int u = __float_as_uint(f);
    unsigned int r = (u + 0x7fffu + ((u >> 16) & 1u)) >> 16;
    return (unsigned short)r;
}

__device__ __forceinline__ void gload_lds16(const void* g, void* l) {
    __builtin_amdgcn_global_load_lds(
        (const __attribute__((address_space(1))) unsigned int*)g,
        (__attribute__((address_space(3))) unsigned int*)l, 16, 0, 0);
}

// ---------------- pass 1: packed LDS histograms (src=low16, dst=high16) + per-edge rank ----------------
__global__ __launch_bounds__(256) void hist_pass(const int* __restrict__ src, const int* __restrict__ dst,
        int* __restrict__ part_src, int* __restrict__ part_dst, unsigned short* __restrict__ rank,
        int E, int epc) {
    __shared__ unsigned int hist[RANGE];   // low16: src count, high16: dst count
    int nc = blockIdx.x & (NCHUNK - 1);
    int ec = blockIdx.x >> NCHUNK_LOG;
    int vbase = nc * RANGE;
    for (int i = threadIdx.x; i < RANGE; i += 256) hist[i] = 0;
    __syncthreads();
    int e0 = ec * epc, e1 = min(e0 + epc, E);
    for (int e = e0 + threadIdx.x; e < e1; e += 256) {
        unsigned rs = (unsigned)(src[e] - vbase);
        unsigned rd = (unsigned)(dst[e] - vbase);
        if (rs < RANGE) atomicAdd(&hist[rs], 1u);
        if (rd < RANGE) {
            unsigned old = atomicAdd(&hist[rd], 0x10000u);
            rank[e] = (unsigned short)(old >> 16);   // rank within (ec, dst-node)
        }
    }
    __syncthreads();
    size_t base = (size_t)ec * NPAD2 + vbase;
    for (int i = threadIdx.x; i < RANGE; i += 256) {
        unsigned v = hist[i];
        part_src[base + i] = (int)(v & 0xFFFFu);
        part_dst[base + i] = (int)(v >> 16);
    }
}

// ---------------- reduce partials ----------------
__global__ void reduce_scan(const int* __restrict__ part_src, int* __restrict__ part_dst,
                            float* __restrict__ deg_out, int* __restrict__ cnt_in, int N) {
    int v = blockIdx.x * 256 + threadIdx.x;
    if (v >= N) return;
    int ssum = 0;
    #pragma unroll 8
    for (int ec = 0; ec < ECHUNK; ++ec) ssum += part_src[(size_t)ec * NPAD2 + v];
    deg_out[v] = (float)ssum;
    int run = 0;
    #pragma unroll 8
    for (int ec = 0; ec < ECHUNK; ++ec) {
        size_t idx = (size_t)ec * NPAD2 + v;
        int t = part_dst[idx];
        part_dst[idx] = run;
        run += t;
    }
    cnt_in[v] = run;
}

// ---------------- scan phase 1 + norms ----------------
__global__ __launch_bounds__(256) void scan_blocks(const int* __restrict__ cnt_in,
        float* __restrict__ deg_out_to_norm_src, float* __restrict__ norm_dst,
        int* __restrict__ row_ptr, int* __restrict__ block_sums, int N) {
    __shared__ int wave_sums[4];
    int b = blockIdx.x;
    int tid = threadIdx.x;
    int lane = tid & 63, w = tid >> 6;
    int idx = b * 1024 + tid * 4;
    int4 v = {0, 0, 0, 0};
    if (idx + 3 < N) v = *(const int4*)(cnt_in + idx);
    else {
        if (idx + 0 < N) v.x = cnt_in[idx + 0];
        if (idx + 1 < N) v.y = cnt_in[idx + 1];
        if (idx + 2 < N) v.z = cnt_in[idx + 2];
        if (idx + 3 < N) v.w = cnt_in[idx + 3];
    }
    int tsum = v.x + v.y + v.z + v.w;
    int s = tsum;
    #pragma unroll
    for (int off = 1; off < 64; off <<= 1) {
        int t = __shfl_up(s, off, 64);
        if (lane >= off) s += t;
    }
    if (lane == 63) wave_sums[w] = s;
    __syncthreads();
    int woff = 0;
    for (int i = 0; i < w; ++i) woff += wave_sums[i];
    int excl = woff + s - tsum;
    int p0 = excl, p1 = p0 + v.x, p2 = p1 + v.y, p3 = p2 + v.z;
    if (idx + 3 < N) {
        *(int4*)(row_ptr + idx) = make_int4(p0, p1, p2, p3);
        float4 d = *(const float4*)(deg_out_to_norm_src + idx);
        float4 ns, nd;
        ns.x = d.x > 0.f ? rsqrtf(d.x) : 0.f;
        ns.y = d.y > 0.f ? rsqrtf(d.y) : 0.f;
        ns.z = d.z > 0.f ? rsqrtf(d.z) : 0.f;
        ns.w = d.w > 0.f ? rsqrtf(d.w) : 0.f;
        nd.x = v.x > 0 ? rsqrtf((float)v.x) : 0.f;
        nd.y = v.y > 0 ? rsqrtf((float)v.y) : 0.f;
        nd.z = v.z > 0 ? rsqrtf((float)v.z) : 0.f;
        nd.w = v.w > 0 ? rsqrtf((float)v.w) : 0.f;
        *(float4*)(deg_out_to_norm_src + idx) = ns;
        *(float4*)(norm_dst + idx) = nd;
    } else {
        int ps[4] = {p0, p1, p2, p3};
        int cs[4] = {v.x, v.y, v.z, v.w};
        for (int j = 0; j < 4; ++j) {
            int i2 = idx + j;
            if (i2 < N) {
                row_ptr[i2] = ps[j];
                float d = deg_out_to_norm_src[i2];
                deg_out_to_norm_src[i2] = d > 0.f ? rsqrtf(d) : 0.f;
                norm_dst[i2] = cs[j] > 0 ? rsqrtf((float)cs[j]) : 0.f;
            }
        }
    }
    if (tid == 255) block_sums[b] = woff + s;
}

// ---------------- scan phase 2 ----------------
__global__ void scan_totals(int* __restrict__ bs, int nb) {
    int lane = threadIdx.x;
    int carry = 0;
    for (int base = 0; base < nb; base += 64) {
        int i = base + lane;
        int v = (i < nb) ? bs[i] : 0;
        int s = v;
        #pragma unroll
        for (int off = 1; off < 64; off <<= 1) {
            int t = __shfl_up(s, off, 64);
            if (lane >= off) s += t;
        }
        if (i < nb) bs[i] = carry + s - v;
        carry += __shfl(s, 63, 64);
    }
}

// ---------------- scan phase 3 ----------------
__global__ void scan_add(int* __restrict__ row_ptr, const int* __restrict__ block_off, int N, int E) {
    int i = blockIdx.x * blockDim.x + threadIdx.x;
    if (i == 0) row_ptr[N] = E;
    if (i < N) row_ptr[i] += block_off[i >> 10];
}

// ---------------- pass 2: flat CSR scatter using precomputed ranks ----------------
__global__ __launch_bounds__(256) void csr_scatter(const int* __restrict__ src, const int* __restrict__ dst,
        const unsigned short* __restrict__ rank, const int* __restrict__ row_ptr,
        const int* __restrict__ chunk_off, int* __restrict__ csr_src, int E, int epc, int bpc) {
    int ec = blockIdx.x / bpc;
    int off = (blockIdx.x - ec * bpc) * 256 + threadIdx.x;
    if (off >= epc) return;
    int e = ec * epc + off;
    if (e >= E) return;
    int d = dst[e];
    int pos = row_ptr[d] + chunk_off[(size_t)ec * NPAD2 + d] + (int)rank[e];
    csr_src[pos] = src[e];
}

// ---------------- conversions ----------------
__global__ void cvt_x(const float* __restrict__ x, const float* __restrict__ norm_src,
                      unsigned short* __restrict__ hs, int N) {
    int i = blockIdx.x * blockDim.x + threadIdx.x;
    if (i >= N * 64) return;
    int node = i >> 6;
    int c4 = (i & 63) << 2;
    float4 v = *(const float4*)(x + (size_t)node * 256 + c4);
    float f = norm_src[node];
    ushort4 o;
    o.x = f2bf(v.x * f); o.y = f2bf(v.y * f); o.z = f2bf(v.z * f); o.w = f2bf(v.w * f);
    *(ushort4*)(hs + (size_t)node * 256 + c4) = o;
}

__global__ void cvt_w_all(const float* __restrict__ W0, const float* __restrict__ W1,
                          const float* __restrict__ W2, const float* __restrict__ Wfc,
                          unsigned short* __restrict__ T0, unsigned short* __restrict__ T1,
                          unsigned short* __restrict__ T2, unsigned short* __restrict__ Tfc) {
    int idx = blockIdx.x * 256 + threadIdx.x;
    if (idx < 3 * 65536) {
        int l = idx >> 16, r = idx & 65535;
        const float* W = (l == 0) ? W0 : (l == 1) ? W1 : W2;
        unsigned short* T = (l == 0) ? T0 : (l == 1) ? T1 : T2;
        int n = r >> 8, k = r & 255;
        T[r] = f2bf(W[(size_t)k * 256 + n]);
    } else {
        int r = idx - 3 * 65536;
        if (r < 128 * 256) {
            int n = r >> 8, k = r & 255;
            Tfc[r] = f2bf((n < 64) ? Wfc[(size_t)k * 64 + n] : 0.f);
        }
    }
}

// ---------------- aggregation: one wave per node, 2 edges per load, 4 loads in flight ----------------
__global__ __launch_bounds__(256) void aggregate_bf16(const unsigned short* __restrict__ h,
                          const int* __restrict__ csr_src, const int* __restrict__ row_ptr,
                          const float* __restrict__ norm_dst,
                          unsigned short* __restrict__ out, int N) {
    int node = (blockIdx.x * blockDim.x + threadIdx.x) >> 6;
    int lane = threadIdx.x & 63;
    if (node >= N) return;
    int beg = row_ptr[node], end = row_ptr[node + 1];
    int half = lane >> 5;
    int cg = (lane & 31) << 3;
    float acc[8] = {};
    int e = beg;
    for (; e + 7 < end; e += 8) {
        int i0 = csr_src[e + half];
        int i1 = csr_src[e + 2 + half];
        int i2 = csr_src[e + 4 + half];
        int i3 = csr_src[e + 6 + half];
        ushort8v v0 = *(const ushort8v*)(h + (size_t)i0 * 256 + cg);
        ushort8v v1 = *(const ushort8v*)(h + (size_t)i1 * 256 + cg);
        ushort8v v2 = *(const ushort8v*)(h + (size_t)i2 * 256 + cg);
        ushort8v v3 = *(const ushort8v*)(h + (size_t)i3 * 256 + cg);
        #pragma unroll
        for (int j = 0; j < 8; ++j)
            acc[j] += (bf2f(v0[j]) + bf2f(v1[j])) + (bf2f(v2[j]) + bf2f(v3[j]));
    }
    for (; e + 1 < end; e += 2) {
        int i0 = csr_src[e + half];
        ushort8v v0 = *(const ushort8v*)(h + (size_t)i0 * 256 + cg);
        #pragma unroll
        for (int j = 0; j < 8; ++j) acc[j] += bf2f(v0[j]);
    }
    if (e < end && half == 0) {
        int i0 = csr_src[e];
        ushort8v v0 = *(const ushort8v*)(h + (size_t)i0 * 256 + cg);
        #pragma unroll
        for (int j = 0; j < 8; ++j) acc[j] += bf2f(v0[j]);
    }
    #pragma unroll
    for (int j = 0; j < 8; ++j) acc[j] += __shfl_xor(acc[j], 32, 64);
    if (half == 0) {
        float nd = norm_dst[node];
        ushort8v o;
        #pragma unroll
        for (int j = 0; j < 8; ++j) o[j] = f2bf(acc[j] * nd);
        *(ushort8v*)(out + (size_t)node * 256 + cg) = o;
    }
}

// ---------------- MFMA GEMM: 2-phase dbuf staging, LDS-relayout C-write, stats partials ----------------
__global__ __launch_bounds__(256) void gemm_mfma(const unsigned short* __restrict__ A,
                          const unsigned short* __restrict__ Bt,
                          const float* __restrict__ bias, float* __restrict__ Cf,
                          unsigned short* __restrict__ Cbf,
                          float* __restrict__ statsPart, int M, int ncols) {
    __shared__ char smem[32768];          // [A dbuf 16KB][B dbuf 16KB]; reused as 4x8KB C-tiles
    __shared__ float sstat[256];
    int tid = threadIdx.x;
    int wid = tid >> 6, lane = tid & 63;
    int wm = wid >> 1, wn = wid & 1;
    size_t row0 = (size_t)blockIdx.x * 128;
    int n0 = blockIdx.y * 128;
    f32x4 acc[4][4] = {};
    const char* Ab = (const char*)(A + row0 * 256);
    const char* Bb = (const char*)(Bt + (size_t)n0 * 256);
    char* AsB = smem;
    char* BsB = smem + 16384;
    if (tid < 256) sstat[tid] = 0.f;

    auto STAGE = [&](int buf, int k0) {
        #pragma unroll
        for (int j = 0; j < 2; ++j) {
            int boff = (wid * 2 + j) * 1024 + lane * 16;
            int row = boff >> 6, col = boff & 63;
            gload_lds16(Ab + (size_t)row * 512 + (size_t)k0 * 2 + col, AsB + buf * 8192 + (wid * 2 + j) * 1024);
            gload_lds16(Bb + (size_t)row * 512 + (size_t)k0 * 2 + col, BsB + buf * 8192 + (wid * 2 + j) * 1024);
        }
    };

    STAGE(0, 0);
    __syncthreads();
    for (int t = 0; t < 8; ++t) {
        int cur = t & 1;
        if (t < 7) STAGE(cur ^ 1, (t + 1) * 32);
        const char* Ac = AsB + cur * 8192;
        const char* Bc = BsB + cur * 8192;
        bfv8 af[4], bfr[4];
        #pragma unroll
        for (int m = 0; m < 4; ++m)
            af[m] = *(const bfv8*)(Ac + ((wm * 64 + m * 16 + (lane & 15)) * 64 + (lane >> 4) * 16));
        #pragma unroll
        for (int n = 0; n < 4; ++n)
            bfr[n] = *(const bfv8*)(Bc + ((wn * 64 + n * 16 + (lane & 15)) * 64 + (lane >> 4) * 16));
        #pragma unroll
        for (int m = 0; m < 4; ++m)
            #pragma unroll
            for (int n = 0; n < 4; ++n)
                acc[m][n] = __builtin_amdgcn_mfma_f32_16x16x32_bf16(af[m], bfr[n], acc[m][n], 0, 0, 0);
        __syncthreads();
    }

    if (statsPart) {
        #pragma unroll
        for (int n = 0; n < 4; ++n) {
            float s1 = 0.f, s2 = 0.f;
            #pragma unroll
            for (int m = 0; m < 4; ++m) {
                size_t rbase = row0 + wm * 64 + m * 16 + ((lane >> 4) << 2);
                #pragma unroll
                for (int r = 0; r < 4; ++r) {
                    float v = ((rbase + r) < (size_t)M) ? acc[m][n][r] : 0.f;
                    s1 += v;
                    s2 += v * v;
                }
            }
            s1 += __shfl_xor(s1, 16, 64); s1 += __shfl_xor(s1, 32, 64);
            s2 += __shfl_xor(s2, 16, 64); s2 += __shfl_xor(s2, 32, 64);
            if (lane < 16) {
                int lc = wn * 64 + n * 16 + lane;
                atomicAdd(&sstat[lc], s1);
                atomicAdd(&sstat[128 + lc], s2);
            }
        }
        __syncthreads();
        if (tid < 256)
            statsPart[((size_t)blockIdx.x * gridDim.y + blockIdx.y) * 256 + tid] = sstat[tid];
    }

    if (Cbf) {
        char* creg = smem + wid * 8192;
        #pragma unroll
        for (int m = 0; m < 4; ++m)
            #pragma unroll
            for (int n = 0; n < 4; ++n) {
                int col = n * 16 + (lane & 15);
                #pragma unroll
                for (int r = 0; r < 4; ++r) {
                    int row = m * 16 + ((lane >> 4) << 2) + r;
                    *(unsigned short*)(creg + row * 128 + col * 2) = f2bf(acc[m][n][r]);
                }
            }
        #pragma unroll
        for (int p = 0; p < 8; ++p) {
            int row = p * 8 + (lane >> 3);
            int slot = lane & 7;
            size_t grow = row0 + wm * 64 + row;
            if (grow < (size_t)M)
                *(ushort8v*)(Cbf + grow * ncols + n0 + wn * 64 + slot * 8) =
                    *(const ushort8v*)(creg + row * 128 + slot * 16);
        }
    } else {
        #pragma unroll
        for (int n = 0; n < 4; ++n) {
            int col = n0 + wn * 64 + n * 16 + (lane & 15);
            if (col < ncols) {
                float b = bias ? bias[col] : 0.0f;
                #pragma unroll
                for (int m = 0; m < 4; ++m) {
                    size_t rbase = row0 + wm * 64 + m * 16 + ((lane >> 4) << 2);
                    #pragma unroll
                    for (int r = 0; r < 4; ++r) {
                        size_t row = rbase + r;
                        if (row < (size_t)M)
                            Cf[row * ncols + col] = acc[m][n][r] + b;
                    }
                }
            }
        }
    }
}

// ---------------- BN finalize: reduce partials + compute scale/shift (one block) ----------------
__global__ void bn_finalize(const float* __restrict__ part, const float* __restrict__ g,
                            const float* __restrict__ beta, float* __restrict__ ss,
                            float invN, int nbx) {
    int c = threadIdx.x;   // 256 channels
    int by = c >> 7, elem = c & 127;
    float s1 = 0.f, s2 = 0.f;
    for (int bx = 0; bx < nbx; ++bx) {
        const float* p = part + ((size_t)bx * 2 + by) * 256;
        s1 += p[elem];
        s2 += p[128 + elem];
    }
    float m = s1 * invN;
    float var = s2 * invN - m * m;
    float sc = g[c] * rsqrtf(var + EPSV);
    ss[c] = sc;
    ss[256 + c] = beta[c] - m * sc;
}

// ---------------- BN apply (bf16 in, bf16 out) ----------------
__global__ void bn_relu_cvt(const unsigned short* __restrict__ y, const float* __restrict__ ss,
                            const float* __restrict__ norm_src, unsigned short* __restrict__ out,
                            int N, int fold) {
    int i = blockIdx.x * blockDim.x + threadIdx.x;
    if (i >= N * 64) return;
    int node = i >> 6;
    int c4 = (i & 63) << 2;
    float4 sc = *(const float4*)(ss + c4);
    float4 sh = *(const float4*)(ss + 256 + c4);
    ushort4 yv = *(const ushort4*)(y + (size_t)node * 256 + c4);
    float f = fold ? norm_src[node] : 1.0f;
    ushort4 o;
    o.x = f2bf(fmaxf(0.f, bf2f(yv.x) * sc.x + sh.x) * f);
    o.y = f2bf(fmaxf(0.f, bf2f(yv.y) * sc.y + sh.y) * f);
    o.z = f2bf(fmaxf(0.f, bf2f(yv.z) * sc.z + sh.z) * f);
    o.w = f2bf(fmaxf(0.f, bf2f(yv.w) * sc.w + sh.w) * f);
    *(ushort4*)(out + (size_t)node * 256 + c4) = o;
}

// ---------------- launch ----------------
extern "C" void kernel_launch(void* const* d_in, const int* in_sizes, int n_in,
                              void* d_out, int out_size, void* d_ws, size_t ws_size,
                              hipStream_t stream) {
    const float* x   = (const float*)d_in[0];
    const int* src   = (const int*)d_in[1];
    const int* dst   = (const int*)d_in[2];
    const float* Ws_[3]    = {(const float*)d_in[3], (const float*)d_in[7],  (const float*)d_in[11]};
    const float* gs_[3]    = {(const float*)d_in[5], (const float*)d_in[9],  (const float*)d_in[13]};
    const float* betas_[3] = {(const float*)d_in[6], (const float*)d_in[10], (const float*)d_in[14]};
    const float* fcW = (const float*)d_in[15];
    const float* fcb = (const float*)d_in[16];
    float* out = (float*)d_out;

    const int N = in_sizes[0] / C_IN;
    const int E = in_sizes[1];
    const int Npad = ((N + 127) / 128) * 128;
    const int nScanBlocks = (N + 1023) / 1024;
    const int epc = (E + ECHUNK - 1) / ECHUNK;
    const int bpc = (epc + 255) / 256;
    const int gemm_rows = Npad / 128;

    char* ws = (char*)d_ws;
    size_t o = 0;
    auto alloc = [&](size_t bytes) { size_t p = o; o = (o + bytes + 511) & ~(size_t)511; return p; };
    float* norm_src = (float*)(ws + alloc((size_t)N * 4));
    int* cnt_in     = (int*)(ws + alloc((size_t)N * 4));
    float* norm_dst = (float*)(ws + alloc((size_t)N * 4));
    int* row_ptr    = (int*)(ws + alloc((size_t)(N + 1) * 4));
    int* block_sums = (int*)(ws + alloc((size_t)(nScanBlocks + 1) * 4));
    int* csr_src    = (int*)(ws + alloc((size_t)E * 4));
    unsigned short* rank = (unsigned short*)(ws + alloc((size_t)E * 2));
    int* part_src   = (int*)(ws + alloc((size_t)ECHUNK * NPAD2 * 4));
    int* part_dst   = (int*)(ws + alloc((size_t)ECHUNK * NPAD2 * 4));
    float* statsPart= (float*)(ws + alloc((size_t)gemm_rows * 2 * 256 * 4));
    float* ss       = (float*)(ws + alloc(512 * 4));
    unsigned short* Wt[3];
    Wt[0] = (unsigned short*)(ws + alloc(256 * 256 * 2));
    Wt[1] = (unsigned short*)(ws + alloc(256 * 256 * 2));
    Wt[2] = (unsigned short*)(ws + alloc(256 * 256 * 2));
    unsigned short* Wtfc = (unsigned short*)(ws + alloc(128 * 256 * 2));
    unsigned short* hbuf   = (unsigned short*)(ws + alloc((size_t)Npad * 256 * 2));
    unsigned short* aggbuf = (unsigned short*)(ws + alloc((size_t)Npad * 256 * 2));
    unsigned short* ybuf   = (unsigned short*)(ws + alloc((size_t)Npad * 256 * 2));
    (void)ws_size; (void)n_in; (void)out_size;

    // graph prep: no global atomics anywhere
    hist_pass<<<NCHUNK * ECHUNK, 256, 0, stream>>>(src, dst, part_src, part_dst, rank, E, epc);
    reduce_scan<<<(N + 255) / 256, 256, 0, stream>>>(part_src, part_dst, norm_src, cnt_in, N);
    scan_blocks<<<nScanBlocks, 256, 0, stream>>>(cnt_in, norm_src, norm_dst, row_ptr, block_sums, N);
    scan_totals<<<1, 64, 0, stream>>>(block_sums, nScanBlocks);
    scan_add<<<(N + 255) / 256, 256, 0, stream>>>(row_ptr, block_sums, N, E);
    csr_scatter<<<ECHUNK * bpc, 256, 0, stream>>>(src, dst, rank, row_ptr, part_dst, csr_src, E, epc, bpc);

    cvt_w_all<<<(3 * 65536 + 128 * 256 + 255) / 256, 256, 0, stream>>>(
        Ws_[0], Ws_[1], Ws_[2], fcW, Wt[0], Wt[1], Wt[2], Wtfc);

    int nb64 = (N * 64 + 255) / 256;
    cvt_x<<<nb64, 256, 0, stream>>>(x, norm_src, hbuf, N);

    int agg_blocks = (N + 3) / 4;
    float invN = 1.0f / (float)N;

    for (int layer = 0; layer < 3; ++layer) {
        aggregate_bf16<<<agg_blocks, 256, 0, stream>>>(hbuf, csr_src, row_ptr, norm_dst, aggbuf, N);
        gemm_mfma<<<dim3(gemm_rows, 2), 256, 0, stream>>>(aggbuf, Wt[layer], nullptr, nullptr, ybuf,
                                                          statsPart, N, C_HID);
        bn_finalize<<<1, 256, 0, stream>>>(statsPart, gs_[layer], betas_[layer], ss, invN, gemm_rows);
        bn_relu_cvt<<<nb64, 256, 0, stream>>>(ybuf, ss, norm_src, hbuf, N, layer < 2 ? 1 : 0);
    }
    gemm_mfma<<<dim3(gemm_rows, 1), 256, 0, stream>>>(hbuf, Wtfc, fcb, out, nullptr, nullptr, N, C_OUT);
}

// Round 11
// 408.541 us; speedup vs baseline: 1.5696x; 1.5696x over previous
//
#include <hip/hip_runtime.h>
#include <hip/hip_bf16.h>

#define C_IN 256
#define C_HID 256
#define C_OUT 64
#define EPSV 1e-5f

// graph-prep histogram geometry
#define NCHUNK 16
#define NCHUNK_LOG 4
#define RANGE 3136           // 16*3136 = 50176 >= N
#define NPAD2 (NCHUNK * RANGE)
#define ECHUNK 64

typedef __bf16 bfv8 __attribute__((ext_vector_type(8)));
typedef float f32x4 __attribute__((ext_vector_type(4)));
typedef unsigned short ushort8v __attribute__((ext_vector_type(8)));

__device__ __forceinline__ float bf2f(unsigned short u) {
    return __uint_as_float(((unsigned int)u) << 16);
}
__device__ __forceinline__ unsigned short f2bf(float f) {
    unsigned int u = __float_as_uint(f);
    unsigned int r = (u + 0x7fffu + ((u >> 16) & 1u)) >> 16;
    return (unsigned short)r;
}

__device__ __forceinline__ void gload_lds16(const void* g, void* l) {
    __builtin_amdgcn_global_load_lds(
        (const __attribute__((address_space(1))) unsigned int*)g,
        (__attribute__((address_space(3))) unsigned int*)l, 16, 0, 0);
}

// ---------------- pass 1: packed LDS histograms (src=low16, dst=high16) + per-edge rank ----------------
__global__ __launch_bounds__(256) void hist_pass(const int* __restrict__ src, const int* __restrict__ dst,
        int* __restrict__ part_src, int* __restrict__ part_dst, unsigned short* __restrict__ rank,
        int E, int epc) {
    __shared__ unsigned int hist[RANGE];   // low16: src count, high16: dst count
    int nc = blockIdx.x & (NCHUNK - 1);
    int ec = blockIdx.x >> NCHUNK_LOG;
    int vbase = nc * RANGE;
    for (int i = threadIdx.x; i < RANGE; i += 256) hist[i] = 0;
    __syncthreads();
    int e0 = ec * epc, e1 = min(e0 + epc, E);
    for (int e = e0 + threadIdx.x; e < e1; e += 256) {
        unsigned rs = (unsigned)(src[e] - vbase);
        unsigned rd = (unsigned)(dst[e] - vbase);
        if (rs < RANGE) atomicAdd(&hist[rs], 1u);
        if (rd < RANGE) {
            unsigned old = atomicAdd(&hist[rd], 0x10000u);
            rank[e] = (unsigned short)(old >> 16);   // rank within (ec, dst-node)
        }
    }
    __syncthreads();
    size_t base = (size_t)ec * NPAD2 + vbase;
    for (int i = threadIdx.x; i < RANGE; i += 256) {
        unsigned v = hist[i];
        part_src[base + i] = (int)(v & 0xFFFFu);
        part_dst[base + i] = (int)(v >> 16);
    }
}

// ---------------- reduce partials ----------------
__global__ void reduce_scan(const int* __restrict__ part_src, int* __restrict__ part_dst,
                            float* __restrict__ deg_out, int* __restrict__ cnt_in, int N) {
    int v = blockIdx.x * 256 + threadIdx.x;
    if (v >= N) return;
    int ssum = 0;
    #pragma unroll 8
    for (int ec = 0; ec < ECHUNK; ++ec) ssum += part_src[(size_t)ec * NPAD2 + v];
    deg_out[v] = (float)ssum;
    int run = 0;
    #pragma unroll 8
    for (int ec = 0; ec < ECHUNK; ++ec) {
        size_t idx = (size_t)ec * NPAD2 + v;
        int t = part_dst[idx];
        part_dst[idx] = run;
        run += t;
    }
    cnt_in[v] = run;
}

// ---------------- scan phase 1 + norms ----------------
__global__ __launch_bounds__(256) void scan_blocks(const int* __restrict__ cnt_in,
        float* __restrict__ deg_out_to_norm_src, float* __restrict__ norm_dst,
        int* __restrict__ row_ptr, int* __restrict__ block_sums, int N) {
    __shared__ int wave_sums[4];
    int b = blockIdx.x;
    int tid = threadIdx.x;
    int lane = tid & 63, w = tid >> 6;
    int idx = b * 1024 + tid * 4;
    int4 v = {0, 0, 0, 0};
    if (idx + 3 < N) v = *(const int4*)(cnt_in + idx);
    else {
        if (idx + 0 < N) v.x = cnt_in[idx + 0];
        if (idx + 1 < N) v.y = cnt_in[idx + 1];
        if (idx + 2 < N) v.z = cnt_in[idx + 2];
        if (idx + 3 < N) v.w = cnt_in[idx + 3];
    }
    int tsum = v.x + v.y + v.z + v.w;
    int s = tsum;
    #pragma unroll
    for (int off = 1; off < 64; off <<= 1) {
        int t = __shfl_up(s, off, 64);
        if (lane >= off) s += t;
    }
    if (lane == 63) wave_sums[w] = s;
    __syncthreads();
    int woff = 0;
    for (int i = 0; i < w; ++i) woff += wave_sums[i];
    int excl = woff + s - tsum;
    int p0 = excl, p1 = p0 + v.x, p2 = p1 + v.y, p3 = p2 + v.z;
    if (idx + 3 < N) {
        *(int4*)(row_ptr + idx) = make_int4(p0, p1, p2, p3);
        float4 d = *(const float4*)(deg_out_to_norm_src + idx);
        float4 ns, nd;
        ns.x = d.x > 0.f ? rsqrtf(d.x) : 0.f;
        ns.y = d.y > 0.f ? rsqrtf(d.y) : 0.f;
        ns.z = d.z > 0.f ? rsqrtf(d.z) : 0.f;
        ns.w = d.w > 0.f ? rsqrtf(d.w) : 0.f;
        nd.x = v.x > 0 ? rsqrtf((float)v.x) : 0.f;
        nd.y = v.y > 0 ? rsqrtf((float)v.y) : 0.f;
        nd.z = v.z > 0 ? rsqrtf((float)v.z) : 0.f;
        nd.w = v.w > 0 ? rsqrtf((float)v.w) : 0.f;
        *(float4*)(deg_out_to_norm_src + idx) = ns;
        *(float4*)(norm_dst + idx) = nd;
    } else {
        int ps[4] = {p0, p1, p2, p3};
        int cs[4] = {v.x, v.y, v.z, v.w};
        for (int j = 0; j < 4; ++j) {
            int i2 = idx + j;
            if (i2 < N) {
                row_ptr[i2] = ps[j];
                float d = deg_out_to_norm_src[i2];
                deg_out_to_norm_src[i2] = d > 0.f ? rsqrtf(d) : 0.f;
                norm_dst[i2] = cs[j] > 0 ? rsqrtf((float)cs[j]) : 0.f;
            }
        }
    }
    if (tid == 255) block_sums[b] = woff + s;
}

// ---------------- scan phase 2 ----------------
__global__ void scan_totals(int* __restrict__ bs, int nb) {
    int lane = threadIdx.x;
    int carry = 0;
    for (int base = 0; base < nb; base += 64) {
        int i = base + lane;
        int v = (i < nb) ? bs[i] : 0;
        int s = v;
        #pragma unroll
        for (int off = 1; off < 64; off <<= 1) {
            int t = __shfl_up(s, off, 64);
            if (lane >= off) s += t;
        }
        if (i < nb) bs[i] = carry + s - v;
        carry += __shfl(s, 63, 64);
    }
}

// ---------------- scan phase 3 ----------------
__global__ void scan_add(int* __restrict__ row_ptr, const int* __restrict__ block_off, int N, int E) {
    int i = blockIdx.x * blockDim.x + threadIdx.x;
    if (i == 0) row_ptr[N] = E;
    if (i < N) row_ptr[i] += block_off[i >> 10];
}

// ---------------- pass 2: flat CSR scatter using precomputed ranks ----------------
__global__ __launch_bounds__(256) void csr_scatter(const int* __restrict__ src, const int* __restrict__ dst,
        const unsigned short* __restrict__ rank, const int* __restrict__ row_ptr,
        const int* __restrict__ chunk_off, int* __restrict__ csr_src, int E, int epc, int bpc) {
    int ec = blockIdx.x / bpc;
    int off = (blockIdx.x - ec * bpc) * 256 + threadIdx.x;
    if (off >= epc) return;
    int e = ec * epc + off;
    if (e >= E) return;
    int d = dst[e];
    int pos = row_ptr[d] + chunk_off[(size_t)ec * NPAD2 + d] + (int)rank[e];
    csr_src[pos] = src[e];
}

// ---------------- conversions ----------------
__global__ void cvt_x(const float* __restrict__ x, const float* __restrict__ norm_src,
                      unsigned short* __restrict__ hs, int N) {
    int i = blockIdx.x * blockDim.x + threadIdx.x;
    if (i >= N * 64) return;
    int node = i >> 6;
    int c4 = (i & 63) << 2;
    float4 v = *(const float4*)(x + (size_t)node * 256 + c4);
    float f = norm_src[node];
    ushort4 o;
    o.x = f2bf(v.x * f); o.y = f2bf(v.y * f); o.z = f2bf(v.z * f); o.w = f2bf(v.w * f);
    *(ushort4*)(hs + (size_t)node * 256 + c4) = o;
}

__global__ void cvt_w_all(const float* __restrict__ W0, const float* __restrict__ W1,
                          const float* __restrict__ W2, const float* __restrict__ Wfc,
                          unsigned short* __restrict__ T0, unsigned short* __restrict__ T1,
                          unsigned short* __restrict__ T2, unsigned short* __restrict__ Tfc) {
    int idx = blockIdx.x * 256 + threadIdx.x;
    if (idx < 3 * 65536) {
        int l = idx >> 16, r = idx & 65535;
        const float* W = (l == 0) ? W0 : (l == 1) ? W1 : W2;
        unsigned short* T = (l == 0) ? T0 : (l == 1) ? T1 : T2;
        int n = r >> 8, k = r & 255;
        T[r] = f2bf(W[(size_t)k * 256 + n]);
    } else {
        int r = idx - 3 * 65536;
        if (r < 128 * 256) {
            int n = r >> 8, k = r & 255;
            Tfc[r] = f2bf((n < 64) ? Wfc[(size_t)k * 64 + n] : 0.f);
        }
    }
}

// ---------------- aggregation: one wave per node, 2 edges per load, 4 loads in flight ----------------
__global__ __launch_bounds__(256) void aggregate_bf16(const unsigned short* __restrict__ h,
                          const int* __restrict__ csr_src, const int* __restrict__ row_ptr,
                          const float* __restrict__ norm_dst,
                          unsigned short* __restrict__ out, int N) {
    int node = (blockIdx.x * blockDim.x + threadIdx.x) >> 6;
    int lane = threadIdx.x & 63;
    if (node >= N) return;
    int beg = row_ptr[node], end = row_ptr[node + 1];
    int half = lane >> 5;
    int cg = (lane & 31) << 3;
    float acc[8] = {};
    int e = beg;
    for (; e + 7 < end; e += 8) {
        int i0 = csr_src[e + half];
        int i1 = csr_src[e + 2 + half];
        int i2 = csr_src[e + 4 + half];
        int i3 = csr_src[e + 6 + half];
        ushort8v v0 = *(const ushort8v*)(h + (size_t)i0 * 256 + cg);
        ushort8v v1 = *(const ushort8v*)(h + (size_t)i1 * 256 + cg);
        ushort8v v2 = *(const ushort8v*)(h + (size_t)i2 * 256 + cg);
        ushort8v v3 = *(const ushort8v*)(h + (size_t)i3 * 256 + cg);
        #pragma unroll
        for (int j = 0; j < 8; ++j)
            acc[j] += (bf2f(v0[j]) + bf2f(v1[j])) + (bf2f(v2[j]) + bf2f(v3[j]));
    }
    for (; e + 1 < end; e += 2) {
        int i0 = csr_src[e + half];
        ushort8v v0 = *(const ushort8v*)(h + (size_t)i0 * 256 + cg);
        #pragma unroll
        for (int j = 0; j < 8; ++j) acc[j] += bf2f(v0[j]);
    }
    if (e < end && half == 0) {
        int i0 = csr_src[e];
        ushort8v v0 = *(const ushort8v*)(h + (size_t)i0 * 256 + cg);
        #pragma unroll
        for (int j = 0; j < 8; ++j) acc[j] += bf2f(v0[j]);
    }
    #pragma unroll
    for (int j = 0; j < 8; ++j) acc[j] += __shfl_xor(acc[j], 32, 64);
    if (half == 0) {
        float nd = norm_dst[node];
        ushort8v o;
        #pragma unroll
        for (int j = 0; j < 8; ++j) o[j] = f2bf(acc[j] * nd);
        *(ushort8v*)(out + (size_t)node * 256 + cg) = o;
    }
}

// ---------------- MFMA GEMM: 2-phase dbuf staging, LDS-relayout C-write, stats partials ----------------
__global__ __launch_bounds__(256) void gemm_mfma(const unsigned short* __restrict__ A,
                          const unsigned short* __restrict__ Bt,
                          const float* __restrict__ bias, float* __restrict__ Cf,
                          unsigned short* __restrict__ Cbf,
                          float* __restrict__ statsPart, int M, int ncols) {
    __shared__ char smem[32768];          // [A dbuf 16KB][B dbuf 16KB]; reused as 4x8KB C-tiles
    __shared__ float sstat[256];
    int tid = threadIdx.x;
    int wid = tid >> 6, lane = tid & 63;
    int wm = wid >> 1, wn = wid & 1;
    size_t row0 = (size_t)blockIdx.x * 128;
    int n0 = blockIdx.y * 128;
    f32x4 acc[4][4] = {};
    const char* Ab = (const char*)(A + row0 * 256);
    const char* Bb = (const char*)(Bt + (size_t)n0 * 256);
    char* AsB = smem;
    char* BsB = smem + 16384;
    if (tid < 256) sstat[tid] = 0.f;

    auto STAGE = [&](int buf, int k0) {
        #pragma unroll
        for (int j = 0; j < 2; ++j) {
            int boff = (wid * 2 + j) * 1024 + lane * 16;
            int row = boff >> 6, col = boff & 63;
            gload_lds16(Ab + (size_t)row * 512 + (size_t)k0 * 2 + col, AsB + buf * 8192 + (wid * 2 + j) * 1024);
            gload_lds16(Bb + (size_t)row * 512 + (size_t)k0 * 2 + col, BsB + buf * 8192 + (wid * 2 + j) * 1024);
        }
    };

    STAGE(0, 0);
    __syncthreads();
    for (int t = 0; t < 8; ++t) {
        int cur = t & 1;
        if (t < 7) STAGE(cur ^ 1, (t + 1) * 32);
        const char* Ac = AsB + cur * 8192;
        const char* Bc = BsB + cur * 8192;
        bfv8 af[4], bfr[4];
        #pragma unroll
        for (int m = 0; m < 4; ++m)
            af[m] = *(const bfv8*)(Ac + ((wm * 64 + m * 16 + (lane & 15)) * 64 + (lane >> 4) * 16));
        #pragma unroll
        for (int n = 0; n < 4; ++n)
            bfr[n] = *(const bfv8*)(Bc + ((wn * 64 + n * 16 + (lane & 15)) * 64 + (lane >> 4) * 16));
        #pragma unroll
        for (int m = 0; m < 4; ++m)
            #pragma unroll
            for (int n = 0; n < 4; ++n)
                acc[m][n] = __builtin_amdgcn_mfma_f32_16x16x32_bf16(af[m], bfr[n], acc[m][n], 0, 0, 0);
        __syncthreads();
    }

    if (statsPart) {
        #pragma unroll
        for (int n = 0; n < 4; ++n) {
            float s1 = 0.f, s2 = 0.f;
            #pragma unroll
            for (int m = 0; m < 4; ++m) {
                size_t rbase = row0 + wm * 64 + m * 16 + ((lane >> 4) << 2);
                #pragma unroll
                for (int r = 0; r < 4; ++r) {
                    float v = ((rbase + r) < (size_t)M) ? acc[m][n][r] : 0.f;
                    s1 += v;
                    s2 += v * v;
                }
            }
            s1 += __shfl_xor(s1, 16, 64); s1 += __shfl_xor(s1, 32, 64);
            s2 += __shfl_xor(s2, 16, 64); s2 += __shfl_xor(s2, 32, 64);
            if (lane < 16) {
                int lc = wn * 64 + n * 16 + lane;
                atomicAdd(&sstat[lc], s1);
                atomicAdd(&sstat[128 + lc], s2);
            }
        }
        __syncthreads();
        if (tid < 256)
            statsPart[((size_t)blockIdx.x * gridDim.y + blockIdx.y) * 256 + tid] = sstat[tid];
    }

    if (Cbf) {
        char* creg = smem + wid * 8192;
        #pragma unroll
        for (int m = 0; m < 4; ++m)
            #pragma unroll
            for (int n = 0; n < 4; ++n) {
                int col = n * 16 + (lane & 15);
                #pragma unroll
                for (int r = 0; r < 4; ++r) {
                    int row = m * 16 + ((lane >> 4) << 2) + r;
                    *(unsigned short*)(creg + row * 128 + col * 2) = f2bf(acc[m][n][r]);
                }
            }
        #pragma unroll
        for (int p = 0; p < 8; ++p) {
            int row = p * 8 + (lane >> 3);
            int slot = lane & 7;
            size_t grow = row0 + wm * 64 + row;
            if (grow < (size_t)M)
                *(ushort8v*)(Cbf + grow * ncols + n0 + wn * 64 + slot * 8) =
                    *(const ushort8v*)(creg + row * 128 + slot * 16);
        }
    } else {
        #pragma unroll
        for (int n = 0; n < 4; ++n) {
            int col = n0 + wn * 64 + n * 16 + (lane & 15);
            if (col < ncols) {
                float b = bias ? bias[col] : 0.0f;
                #pragma unroll
                for (int m = 0; m < 4; ++m) {
                    size_t rbase = row0 + wm * 64 + m * 16 + ((lane >> 4) << 2);
                    #pragma unroll
                    for (int r = 0; r < 4; ++r) {
                        size_t row = rbase + r;
                        if (row < (size_t)M)
                            Cf[row * ncols + col] = acc[m][n][r] + b;
                    }
                }
            }
        }
    }
}

// ---------------- BN stats reduction (two-stage: 8 blocks then 1 block) ----------------
__global__ void bn_reduce(const float* __restrict__ part, float* __restrict__ part2, int nbx, int chunk) {
    int g = blockIdx.x, t = threadIdx.x;     // grid(8), 512 threads
    int b0 = g * chunk, b1 = min(b0 + chunk, nbx);
    int by, elem;
    if (t < 256) { by = t >> 7; elem = t & 127; }
    else { int c = t - 256; by = c >> 7; elem = 128 + (c & 127); }
    float s = 0.f;
    for (int bx = b0; bx < b1; ++bx)
        s += part[((size_t)bx * 2 + by) * 256 + elem];
    part2[g * 512 + t] = s;
}

__global__ void bn_params(const float* __restrict__ part2, const float* __restrict__ g,
                          const float* __restrict__ beta, float* __restrict__ ss, float invN) {
    int c = threadIdx.x;   // 256
    float s1 = 0.f, s2 = 0.f;
    #pragma unroll
    for (int k = 0; k < 8; ++k) { s1 += part2[k * 512 + c]; s2 += part2[k * 512 + 256 + c]; }
    float m = s1 * invN;
    float var = s2 * invN - m * m;
    float sc = g[c] * rsqrtf(var + EPSV);
    ss[c] = sc;
    ss[256 + c] = beta[c] - m * sc;
}

// ---------------- BN apply (bf16 in, bf16 out) ----------------
__global__ void bn_relu_cvt(const unsigned short* __restrict__ y, const float* __restrict__ ss,
                            const float* __restrict__ norm_src, unsigned short* __restrict__ out,
                            int N, int fold) {
    int i = blockIdx.x * blockDim.x + threadIdx.x;
    if (i >= N * 64) return;
    int node = i >> 6;
    int c4 = (i & 63) << 2;
    float4 sc = *(const float4*)(ss + c4);
    float4 sh = *(const float4*)(ss + 256 + c4);
    ushort4 yv = *(const ushort4*)(y + (size_t)node * 256 + c4);
    float f = fold ? norm_src[node] : 1.0f;
    ushort4 o;
    o.x = f2bf(fmaxf(0.f, bf2f(yv.x) * sc.x + sh.x) * f);
    o.y = f2bf(fmaxf(0.f, bf2f(yv.y) * sc.y + sh.y) * f);
    o.z = f2bf(fmaxf(0.f, bf2f(yv.z) * sc.z + sh.z) * f);
    o.w = f2bf(fmaxf(0.f, bf2f(yv.w) * sc.w + sh.w) * f);
    *(ushort4*)(out + (size_t)node * 256 + c4) = o;
}

// ---------------- launch ----------------
extern "C" void kernel_launch(void* const* d_in, const int* in_sizes, int n_in,
                              void* d_out, int out_size, void* d_ws, size_t ws_size,
                              hipStream_t stream) {
    const float* x   = (const float*)d_in[0];
    const int* src   = (const int*)d_in[1];
    const int* dst   = (const int*)d_in[2];
    const float* Ws_[3]    = {(const float*)d_in[3], (const float*)d_in[7],  (const float*)d_in[11]};
    const float* gs_[3]    = {(const float*)d_in[5], (const float*)d_in[9],  (const float*)d_in[13]};
    const float* betas_[3] = {(const float*)d_in[6], (const float*)d_in[10], (const float*)d_in[14]};
    const float* fcW = (const float*)d_in[15];
    const float* fcb = (const float*)d_in[16];
    float* out = (float*)d_out;

    const int N = in_sizes[0] / C_IN;
    const int E = in_sizes[1];
    const int Npad = ((N + 127) / 128) * 128;
    const int nScanBlocks = (N + 1023) / 1024;
    const int epc = (E + ECHUNK - 1) / ECHUNK;
    const int bpc = (epc + 255) / 256;
    const int gemm_rows = Npad / 128;
    const int chunk = (gemm_rows + 7) / 8;

    char* ws = (char*)d_ws;
    size_t o = 0;
    auto alloc = [&](size_t bytes) { size_t p = o; o = (o + bytes + 511) & ~(size_t)511; return p; };
    float* norm_src = (float*)(ws + alloc((size_t)N * 4));
    int* cnt_in     = (int*)(ws + alloc((size_t)N * 4));
    float* norm_dst = (float*)(ws + alloc((size_t)N * 4));
    int* row_ptr    = (int*)(ws + alloc((size_t)(N + 1) * 4));
    int* block_sums = (int*)(ws + alloc((size_t)(nScanBlocks + 1) * 4));
    int* csr_src    = (int*)(ws + alloc((size_t)E * 4));
    unsigned short* rank = (unsigned short*)(ws + alloc((size_t)E * 2));
    int* part_src   = (int*)(ws + alloc((size_t)ECHUNK * NPAD2 * 4));
    int* part_dst   = (int*)(ws + alloc((size_t)ECHUNK * NPAD2 * 4));
    float* statsPart= (float*)(ws + alloc((size_t)gemm_rows * 2 * 256 * 4));
    float* part2    = (float*)(ws + alloc(8 * 512 * 4));
    float* ss       = (float*)(ws + alloc(512 * 4));
    unsigned short* Wt[3];
    Wt[0] = (unsigned short*)(ws + alloc(256 * 256 * 2));
    Wt[1] = (unsigned short*)(ws + alloc(256 * 256 * 2));
    Wt[2] = (unsigned short*)(ws + alloc(256 * 256 * 2));
    unsigned short* Wtfc = (unsigned short*)(ws + alloc(128 * 256 * 2));
    unsigned short* hbuf   = (unsigned short*)(ws + alloc((size_t)Npad * 256 * 2));
    unsigned short* aggbuf = (unsigned short*)(ws + alloc((size_t)Npad * 256 * 2));
    unsigned short* ybuf   = (unsigned short*)(ws + alloc((size_t)Npad * 256 * 2));
    (void)ws_size; (void)n_in; (void)out_size;

    // graph prep: no global atomics anywhere
    hist_pass<<<NCHUNK * ECHUNK, 256, 0, stream>>>(src, dst, part_src, part_dst, rank, E, epc);
    reduce_scan<<<(N + 255) / 256, 256, 0, stream>>>(part_src, part_dst, norm_src, cnt_in, N);
    scan_blocks<<<nScanBlocks, 256, 0, stream>>>(cnt_in, norm_src, norm_dst, row_ptr, block_sums, N);
    scan_totals<<<1, 64, 0, stream>>>(block_sums, nScanBlocks);
    scan_add<<<(N + 255) / 256, 256, 0, stream>>>(row_ptr, block_sums, N, E);
    csr_scatter<<<ECHUNK * bpc, 256, 0, stream>>>(src, dst, rank, row_ptr, part_dst, csr_src, E, epc, bpc);

    cvt_w_all<<<(3 * 65536 + 128 * 256 + 255) / 256, 256, 0, stream>>>(
        Ws_[0], Ws_[1], Ws_[2], fcW, Wt[0], Wt[1], Wt[2], Wtfc);

    int nb64 = (N * 64 + 255) / 256;
    cvt_x<<<nb64, 256, 0, stream>>>(x, norm_src, hbuf, N);

    int agg_blocks = (N + 3) / 4;
    float invN = 1.0f / (float)N;

    for (int layer = 0; layer < 3; ++layer) {
        aggregate_bf16<<<agg_blocks, 256, 0, stream>>>(hbuf, csr_src, row_ptr, norm_dst, aggbuf, N);
        gemm_mfma<<<dim3(gemm_rows, 2), 256, 0, stream>>>(aggbuf, Wt[layer], nullptr, nullptr, ybuf,
                                                          statsPart, N, C_HID);
        bn_reduce<<<8, 512, 0, stream>>>(statsPart, part2, gemm_rows, chunk);
        bn_params<<<1, 256, 0, stream>>>(part2, gs_[layer], betas_[layer], ss, invN);
        bn_relu_cvt<<<nb64, 256, 0, stream>>>(ybuf, ss, norm_src, hbuf, N, layer < 2 ? 1 : 0);
    }
    gemm_mfma<<<dim3(gemm_rows, 1), 256, 0, stream>>>(hbuf, Wtfc, fcb, out, nullptr, nullptr, N, C_OUT);
}

// Round 12
// 392.114 us; speedup vs baseline: 1.6353x; 1.0419x over previous
//
#include <hip/hip_runtime.h>
#include <hip/hip_bf16.h>

#define C_IN 256
#define C_HID 256
#define C_OUT 64
#define EPSV 1e-5f

// graph-prep histogram geometry
#define NCHUNK 16
#define NCHUNK_LOG 4
#define RANGE 3136           // 16*3136 = 50176 >= N
#define NPAD2 (NCHUNK * RANGE)
#define ECHUNK 64

typedef __bf16 bfv8 __attribute__((ext_vector_type(8)));
typedef float f32x4 __attribute__((ext_vector_type(4)));
typedef unsigned short ushort8v __attribute__((ext_vector_type(8)));

__device__ __forceinline__ float bf2f(unsigned short u) {
    return __uint_as_float(((unsigned int)u) << 16);
}
__device__ __forceinline__ unsigned short f2bf(float f) {
    unsigned int u = __float_as_uint(f);
    unsigned int r = (u + 0x7fffu + ((u >> 16) & 1u)) >> 16;
    return (unsigned short)r;
}

__device__ __forceinline__ void gload_lds16(const void* g, void* l) {
    __builtin_amdgcn_global_load_lds(
        (const __attribute__((address_space(1))) unsigned int*)g,
        (__attribute__((address_space(3))) unsigned int*)l, 16, 0, 0);
}

// ---------------- pass 1: packed LDS histograms (src=low16, dst=high16) + per-edge rank ----------------
__global__ __launch_bounds__(256) void hist_pass(const int* __restrict__ src, const int* __restrict__ dst,
        int* __restrict__ part_src, int* __restrict__ part_dst, unsigned short* __restrict__ rank,
        int E, int epc) {
    __shared__ unsigned int hist[RANGE];   // low16: src count, high16: dst count
    int nc = blockIdx.x & (NCHUNK - 1);
    int ec = blockIdx.x >> NCHUNK_LOG;
    int vbase = nc * RANGE;
    for (int i = threadIdx.x; i < RANGE; i += 256) hist[i] = 0;
    __syncthreads();
    int e0 = ec * epc, e1 = min(e0 + epc, E);
    for (int e = e0 + threadIdx.x; e < e1; e += 256) {
        unsigned rs = (unsigned)(src[e] - vbase);
        unsigned rd = (unsigned)(dst[e] - vbase);
        if (rs < RANGE) atomicAdd(&hist[rs], 1u);
        if (rd < RANGE) {
            unsigned old = atomicAdd(&hist[rd], 0x10000u);
            rank[e] = (unsigned short)(old >> 16);   // rank within (ec, dst-node)
        }
    }
    __syncthreads();
    size_t base = (size_t)ec * NPAD2 + vbase;
    for (int i = threadIdx.x; i < RANGE; i += 256) {
        unsigned v = hist[i];
        part_src[base + i] = (int)(v & 0xFFFFu);
        part_dst[base + i] = (int)(v >> 16);
    }
}

// ---------------- reduce partials ----------------
__global__ void reduce_scan(const int* __restrict__ part_src, int* __restrict__ part_dst,
                            float* __restrict__ deg_out, int* __restrict__ cnt_in, int N) {
    int v = blockIdx.x * 256 + threadIdx.x;
    if (v >= N) return;
    int ssum = 0;
    #pragma unroll 8
    for (int ec = 0; ec < ECHUNK; ++ec) ssum += part_src[(size_t)ec * NPAD2 + v];
    deg_out[v] = (float)ssum;
    int run = 0;
    #pragma unroll 8
    for (int ec = 0; ec < ECHUNK; ++ec) {
        size_t idx = (size_t)ec * NPAD2 + v;
        int t = part_dst[idx];
        part_dst[idx] = run;
        run += t;
    }
    cnt_in[v] = run;
}

// ---------------- scan phase 1 + norms ----------------
__global__ __launch_bounds__(256) void scan_blocks(const int* __restrict__ cnt_in,
        float* __restrict__ deg_out_to_norm_src, float* __restrict__ norm_dst,
        int* __restrict__ row_ptr, int* __restrict__ block_sums, int N) {
    __shared__ int wave_sums[4];
    int b = blockIdx.x;
    int tid = threadIdx.x;
    int lane = tid & 63, w = tid >> 6;
    int idx = b * 1024 + tid * 4;
    int4 v = {0, 0, 0, 0};
    if (idx + 3 < N) v = *(const int4*)(cnt_in + idx);
    else {
        if (idx + 0 < N) v.x = cnt_in[idx + 0];
        if (idx + 1 < N) v.y = cnt_in[idx + 1];
        if (idx + 2 < N) v.z = cnt_in[idx + 2];
        if (idx + 3 < N) v.w = cnt_in[idx + 3];
    }
    int tsum = v.x + v.y + v.z + v.w;
    int s = tsum;
    #pragma unroll
    for (int off = 1; off < 64; off <<= 1) {
        int t = __shfl_up(s, off, 64);
        if (lane >= off) s += t;
    }
    if (lane == 63) wave_sums[w] = s;
    __syncthreads();
    int woff = 0;
    for (int i = 0; i < w; ++i) woff += wave_sums[i];
    int excl = woff + s - tsum;
    int p0 = excl, p1 = p0 + v.x, p2 = p1 + v.y, p3 = p2 + v.z;
    if (idx + 3 < N) {
        *(int4*)(row_ptr + idx) = make_int4(p0, p1, p2, p3);
        float4 d = *(const float4*)(deg_out_to_norm_src + idx);
        float4 ns, nd;
        ns.x = d.x > 0.f ? rsqrtf(d.x) : 0.f;
        ns.y = d.y > 0.f ? rsqrtf(d.y) : 0.f;
        ns.z = d.z > 0.f ? rsqrtf(d.z) : 0.f;
        ns.w = d.w > 0.f ? rsqrtf(d.w) : 0.f;
        nd.x = v.x > 0 ? rsqrtf((float)v.x) : 0.f;
        nd.y = v.y > 0 ? rsqrtf((float)v.y) : 0.f;
        nd.z = v.z > 0 ? rsqrtf((float)v.z) : 0.f;
        nd.w = v.w > 0 ? rsqrtf((float)v.w) : 0.f;
        *(float4*)(deg_out_to_norm_src + idx) = ns;
        *(float4*)(norm_dst + idx) = nd;
    } else {
        int ps[4] = {p0, p1, p2, p3};
        int cs[4] = {v.x, v.y, v.z, v.w};
        for (int j = 0; j < 4; ++j) {
            int i2 = idx + j;
            if (i2 < N) {
                row_ptr[i2] = ps[j];
                float d = deg_out_to_norm_src[i2];
                deg_out_to_norm_src[i2] = d > 0.f ? rsqrtf(d) : 0.f;
                norm_dst[i2] = cs[j] > 0 ? rsqrtf((float)cs[j]) : 0.f;
            }
        }
    }
    if (tid == 255) block_sums[b] = woff + s;
}

// ---------------- scan phase 2+3 merged: per-block redundant scan of block sums, then add ----------------
__global__ void scan_add(int* __restrict__ row_ptr, const int* __restrict__ bs, int N, int E, int nb) {
    __shared__ int soff[256];
    int tid = threadIdx.x;
    if (tid < 64) {
        int carry = 0;
        for (int base = 0; base < nb; base += 64) {
            int i = base + tid;
            int v = (i < nb) ? bs[i] : 0;
            int s = v;
            #pragma unroll
            for (int off = 1; off < 64; off <<= 1) {
                int t = __shfl_up(s, off, 64);
                if (tid >= off) s += t;
            }
            if (i < nb && i < 256) soff[i] = carry + s - v;
            carry += __shfl(s, 63, 64);
        }
    }
    __syncthreads();
    int i = blockIdx.x * blockDim.x + tid;
    if (i == 0) row_ptr[N] = E;
    if (i < N) row_ptr[i] += soff[i >> 10];
}

// ---------------- pass 2: flat CSR scatter using precomputed ranks ----------------
__global__ __launch_bounds__(256) void csr_scatter(const int* __restrict__ src, const int* __restrict__ dst,
        const unsigned short* __restrict__ rank, const int* __restrict__ row_ptr,
        const int* __restrict__ chunk_off, int* __restrict__ csr_src, int E, int epc, int bpc) {
    int ec = blockIdx.x / bpc;
    int off = (blockIdx.x - ec * bpc) * 256 + threadIdx.x;
    if (off >= epc) return;
    int e = ec * epc + off;
    if (e >= E) return;
    int d = dst[e];
    int pos = row_ptr[d] + chunk_off[(size_t)ec * NPAD2 + d] + (int)rank[e];
    csr_src[pos] = src[e];
}

// ---------------- conversions ----------------
__global__ void cvt_x(const float* __restrict__ x, const float* __restrict__ norm_src,
                      unsigned short* __restrict__ hs, int N) {
    int i = blockIdx.x * blockDim.x + threadIdx.x;
    if (i >= N * 64) return;
    int node = i >> 6;
    int c4 = (i & 63) << 2;
    float4 v = *(const float4*)(x + (size_t)node * 256 + c4);
    float f = norm_src[node];
    ushort4 o;
    o.x = f2bf(v.x * f); o.y = f2bf(v.y * f); o.z = f2bf(v.z * f); o.w = f2bf(v.w * f);
    *(ushort4*)(hs + (size_t)node * 256 + c4) = o;
}

__global__ void cvt_w_all(const float* __restrict__ W0, const float* __restrict__ W1,
                          const float* __restrict__ W2, const float* __restrict__ Wfc,
                          unsigned short* __restrict__ T0, unsigned short* __restrict__ T1,
                          unsigned short* __restrict__ T2, unsigned short* __restrict__ Tfc) {
    int idx = blockIdx.x * 256 + threadIdx.x;
    if (idx < 3 * 65536) {
        int l = idx >> 16, r = idx & 65535;
        const float* W = (l == 0) ? W0 : (l == 1) ? W1 : W2;
        unsigned short* T = (l == 0) ? T0 : (l == 1) ? T1 : T2;
        int n = r >> 8, k = r & 255;
        T[r] = f2bf(W[(size_t)k * 256 + n]);
    } else {
        int r = idx - 3 * 65536;
        if (r < 128 * 256) {
            int n = r >> 8, k = r & 255;
            Tfc[r] = f2bf((n < 64) ? Wfc[(size_t)k * 64 + n] : 0.f);
        }
    }
}

// ---------------- aggregation (plain): input already BN'd/folded ----------------
__global__ __launch_bounds__(256) void aggregate_bf16(const unsigned short* __restrict__ h,
                          const int* __restrict__ csr_src, const int* __restrict__ row_ptr,
                          const float* __restrict__ norm_dst,
                          unsigned short* __restrict__ out, int N) {
    int node = (blockIdx.x * blockDim.x + threadIdx.x) >> 6;
    int lane = threadIdx.x & 63;
    if (node >= N) return;
    int beg = row_ptr[node], end = row_ptr[node + 1];
    int half = lane >> 5;
    int cg = (lane & 31) << 3;
    float acc[8] = {};
    int e = beg;
    for (; e + 7 < end; e += 8) {
        int i0 = csr_src[e + half];
        int i1 = csr_src[e + 2 + half];
        int i2 = csr_src[e + 4 + half];
        int i3 = csr_src[e + 6 + half];
        ushort8v v0 = *(const ushort8v*)(h + (size_t)i0 * 256 + cg);
        ushort8v v1 = *(const ushort8v*)(h + (size_t)i1 * 256 + cg);
        ushort8v v2 = *(const ushort8v*)(h + (size_t)i2 * 256 + cg);
        ushort8v v3 = *(const ushort8v*)(h + (size_t)i3 * 256 + cg);
        #pragma unroll
        for (int j = 0; j < 8; ++j)
            acc[j] += (bf2f(v0[j]) + bf2f(v1[j])) + (bf2f(v2[j]) + bf2f(v3[j]));
    }
    for (; e + 1 < end; e += 2) {
        int i0 = csr_src[e + half];
        ushort8v v0 = *(const ushort8v*)(h + (size_t)i0 * 256 + cg);
        #pragma unroll
        for (int j = 0; j < 8; ++j) acc[j] += bf2f(v0[j]);
    }
    if (e < end && half == 0) {
        int i0 = csr_src[e];
        ushort8v v0 = *(const ushort8v*)(h + (size_t)i0 * 256 + cg);
        #pragma unroll
        for (int j = 0; j < 8; ++j) acc[j] += bf2f(v0[j]);
    }
    #pragma unroll
    for (int j = 0; j < 8; ++j) acc[j] += __shfl_xor(acc[j], 32, 64);
    if (half == 0) {
        float nd = norm_dst[node];
        ushort8v o;
        #pragma unroll
        for (int j = 0; j < 8; ++j) o[j] = f2bf(acc[j] * nd);
        *(ushort8v*)(out + (size_t)node * 256 + cg) = o;
    }
}

// ---------------- aggregation with fused BN+ReLU+norm_src (reads raw gemm output) ----------------
// acc += norm_src[s] * relu(sc*y[s] + sh), per channel
__global__ __launch_bounds__(256) void aggregate_bn_fused(const unsigned short* __restrict__ y,
                          const float* __restrict__ ss, const float* __restrict__ norm_src,
                          const int* __restrict__ csr_src, const int* __restrict__ row_ptr,
                          const float* __restrict__ norm_dst,
                          unsigned short* __restrict__ out, int N) {
    int node = (blockIdx.x * blockDim.x + threadIdx.x) >> 6;
    int lane = threadIdx.x & 63;
    if (node >= N) return;
    int beg = row_ptr[node], end = row_ptr[node + 1];
    int half = lane >> 5;
    int cg = (lane & 31) << 3;
    float scv[8], shv[8];
    {
        float4 a = *(const float4*)(ss + cg);
        float4 b = *(const float4*)(ss + cg + 4);
        float4 c = *(const float4*)(ss + 256 + cg);
        float4 d = *(const float4*)(ss + 256 + cg + 4);
        scv[0]=a.x; scv[1]=a.y; scv[2]=a.z; scv[3]=a.w; scv[4]=b.x; scv[5]=b.y; scv[6]=b.z; scv[7]=b.w;
        shv[0]=c.x; shv[1]=c.y; shv[2]=c.z; shv[3]=c.w; shv[4]=d.x; shv[5]=d.y; shv[6]=d.z; shv[7]=d.w;
    }
    float acc[8] = {};
    int e = beg;
    for (; e + 7 < end; e += 8) {
        int i0 = csr_src[e + half];
        int i1 = csr_src[e + 2 + half];
        int i2 = csr_src[e + 4 + half];
        int i3 = csr_src[e + 6 + half];
        float n0 = norm_src[i0], n1 = norm_src[i1], n2 = norm_src[i2], n3 = norm_src[i3];
        ushort8v v0 = *(const ushort8v*)(y + (size_t)i0 * 256 + cg);
        ushort8v v1 = *(const ushort8v*)(y + (size_t)i1 * 256 + cg);
        ushort8v v2 = *(const ushort8v*)(y + (size_t)i2 * 256 + cg);
        ushort8v v3 = *(const ushort8v*)(y + (size_t)i3 * 256 + cg);
        #pragma unroll
        for (int j = 0; j < 8; ++j) {
            acc[j] += n0 * fmaxf(0.f, bf2f(v0[j]) * scv[j] + shv[j]);
            acc[j] += n1 * fmaxf(0.f, bf2f(v1[j]) * scv[j] + shv[j]);
            acc[j] += n2 * fmaxf(0.f, bf2f(v2[j]) * scv[j] + shv[j]);
            acc[j] += n3 * fmaxf(0.f, bf2f(v3[j]) * scv[j] + shv[j]);
        }
    }
    for (; e + 1 < end; e += 2) {
        int i0 = csr_src[e + half];
        float n0 = norm_src[i0];
        ushort8v v0 = *(const ushort8v*)(y + (size_t)i0 * 256 + cg);
        #pragma unroll
        for (int j = 0; j < 8; ++j)
            acc[j] += n0 * fmaxf(0.f, bf2f(v0[j]) * scv[j] + shv[j]);
    }
    if (e < end && half == 0) {
        int i0 = csr_src[e];
        float n0 = norm_src[i0];
        ushort8v v0 = *(const ushort8v*)(y + (size_t)i0 * 256 + cg);
        #pragma unroll
        for (int j = 0; j < 8; ++j)
            acc[j] += n0 * fmaxf(0.f, bf2f(v0[j]) * scv[j] + shv[j]);
    }
    #pragma unroll
    for (int j = 0; j < 8; ++j) acc[j] += __shfl_xor(acc[j], 32, 64);
    if (half == 0) {
        float nd = norm_dst[node];
        ushort8v o;
        #pragma unroll
        for (int j = 0; j < 8; ++j) o[j] = f2bf(acc[j] * nd);
        *(ushort8v*)(out + (size_t)node * 256 + cg) = o;
    }
}

// ---------------- MFMA GEMM: 2-phase dbuf staging, LDS-relayout C-write, stats partials ----------------
__global__ __launch_bounds__(256) void gemm_mfma(const unsigned short* __restrict__ A,
                          const unsigned short* __restrict__ Bt,
                          const float* __restrict__ bias, float* __restrict__ Cf,
                          unsigned short* __restrict__ Cbf,
                          float* __restrict__ statsPart, int M, int ncols) {
    __shared__ char smem[32768];          // [A dbuf 16KB][B dbuf 16KB]; reused as 4x8KB C-tiles
    __shared__ float sstat[256];
    int tid = threadIdx.x;
    int wid = tid >> 6, lane = tid & 63;
    int wm = wid >> 1, wn = wid & 1;
    size_t row0 = (size_t)blockIdx.x * 128;
    int n0 = blockIdx.y * 128;
    f32x4 acc[4][4] = {};
    const char* Ab = (const char*)(A + row0 * 256);
    const char* Bb = (const char*)(Bt + (size_t)n0 * 256);
    char* AsB = smem;
    char* BsB = smem + 16384;
    if (tid < 256) sstat[tid] = 0.f;

    auto STAGE = [&](int buf, int k0) {
        #pragma unroll
        for (int j = 0; j < 2; ++j) {
            int boff = (wid * 2 + j) * 1024 + lane * 16;
            int row = boff >> 6, col = boff & 63;
            gload_lds16(Ab + (size_t)row * 512 + (size_t)k0 * 2 + col, AsB + buf * 8192 + (wid * 2 + j) * 1024);
            gload_lds16(Bb + (size_t)row * 512 + (size_t)k0 * 2 + col, BsB + buf * 8192 + (wid * 2 + j) * 1024);
        }
    };

    STAGE(0, 0);
    __syncthreads();
    for (int t = 0; t < 8; ++t) {
        int cur = t & 1;
        if (t < 7) STAGE(cur ^ 1, (t + 1) * 32);
        const char* Ac = AsB + cur * 8192;
        const char* Bc = BsB + cur * 8192;
        bfv8 af[4], bfr[4];
        #pragma unroll
        for (int m = 0; m < 4; ++m)
            af[m] = *(const bfv8*)(Ac + ((wm * 64 + m * 16 + (lane & 15)) * 64 + (lane >> 4) * 16));
        #pragma unroll
        for (int n = 0; n < 4; ++n)
            bfr[n] = *(const bfv8*)(Bc + ((wn * 64 + n * 16 + (lane & 15)) * 64 + (lane >> 4) * 16));
        #pragma unroll
        for (int m = 0; m < 4; ++m)
            #pragma unroll
            for (int n = 0; n < 4; ++n)
                acc[m][n] = __builtin_amdgcn_mfma_f32_16x16x32_bf16(af[m], bfr[n], acc[m][n], 0, 0, 0);
        __syncthreads();
    }

    if (statsPart) {
        #pragma unroll
        for (int n = 0; n < 4; ++n) {
            float s1 = 0.f, s2 = 0.f;
            #pragma unroll
            for (int m = 0; m < 4; ++m) {
                size_t rbase = row0 + wm * 64 + m * 16 + ((lane >> 4) << 2);
                #pragma unroll
                for (int r = 0; r < 4; ++r) {
                    float v = ((rbase + r) < (size_t)M) ? acc[m][n][r] : 0.f;
                    s1 += v;
                    s2 += v * v;
                }
            }
            s1 += __shfl_xor(s1, 16, 64); s1 += __shfl_xor(s1, 32, 64);
            s2 += __shfl_xor(s2, 16, 64); s2 += __shfl_xor(s2, 32, 64);
            if (lane < 16) {
                int lc = wn * 64 + n * 16 + lane;
                atomicAdd(&sstat[lc], s1);
                atomicAdd(&sstat[128 + lc], s2);
            }
        }
        __syncthreads();
        if (tid < 256)
            statsPart[((size_t)blockIdx.x * gridDim.y + blockIdx.y) * 256 + tid] = sstat[tid];
    }

    if (Cbf) {
        char* creg = smem + wid * 8192;
        #pragma unroll
        for (int m = 0; m < 4; ++m)
            #pragma unroll
            for (int n = 0; n < 4; ++n) {
                int col = n * 16 + (lane & 15);
                #pragma unroll
                for (int r = 0; r < 4; ++r) {
                    int row = m * 16 + ((lane >> 4) << 2) + r;
                    *(unsigned short*)(creg + row * 128 + col * 2) = f2bf(acc[m][n][r]);
                }
            }
        #pragma unroll
        for (int p = 0; p < 8; ++p) {
            int row = p * 8 + (lane >> 3);
            int slot = lane & 7;
            size_t grow = row0 + wm * 64 + row;
            if (grow < (size_t)M)
                *(ushort8v*)(Cbf + grow * ncols + n0 + wn * 64 + slot * 8) =
                    *(const ushort8v*)(creg + row * 128 + slot * 16);
        }
    } else {
        #pragma unroll
        for (int n = 0; n < 4; ++n) {
            int col = n0 + wn * 64 + n * 16 + (lane & 15);
            if (col < ncols) {
                float b = bias ? bias[col] : 0.0f;
                #pragma unroll
                for (int m = 0; m < 4; ++m) {
                    size_t rbase = row0 + wm * 64 + m * 16 + ((lane >> 4) << 2);
                    #pragma unroll
                    for (int r = 0; r < 4; ++r) {
                        size_t row = rbase + r;
                        if (row < (size_t)M)
                            Cf[row * ncols + col] = acc[m][n][r] + b;
                    }
                }
            }
        }
    }
}

// ---------------- BN stats reduction (two-stage: 8 blocks then 1 block) ----------------
__global__ void bn_reduce(const float* __restrict__ part, float* __restrict__ part2, int nbx, int chunk) {
    int g = blockIdx.x, t = threadIdx.x;     // grid(8), 512 threads
    int b0 = g * chunk, b1 = min(b0 + chunk, nbx);
    int by, elem;
    if (t < 256) { by = t >> 7; elem = t & 127; }
    else { int c = t - 256; by = c >> 7; elem = 128 + (c & 127); }
    float s = 0.f;
    for (int bx = b0; bx < b1; ++bx)
        s += part[((size_t)bx * 2 + by) * 256 + elem];
    part2[g * 512 + t] = s;
}

__global__ void bn_params(const float* __restrict__ part2, const float* __restrict__ g,
                          const float* __restrict__ beta, float* __restrict__ ss, float invN) {
    int c = threadIdx.x;   // 256
    float s1 = 0.f, s2 = 0.f;
    #pragma unroll
    for (int k = 0; k < 8; ++k) { s1 += part2[k * 512 + c]; s2 += part2[k * 512 + 256 + c]; }
    float m = s1 * invN;
    float var = s2 * invN - m * m;
    float sc = g[c] * rsqrtf(var + EPSV);
    ss[c] = sc;
    ss[256 + c] = beta[c] - m * sc;
}

// ---------------- BN apply (bf16 in, bf16 out) — used only for the last layer before FC ----------------
__global__ void bn_relu_cvt(const unsigned short* __restrict__ y, const float* __restrict__ ss,
                            const float* __restrict__ norm_src, unsigned short* __restrict__ out,
                            int N, int fold) {
    int i = blockIdx.x * blockDim.x + threadIdx.x;
    if (i >= N * 64) return;
    int node = i >> 6;
    int c4 = (i & 63) << 2;
    float4 sc = *(const float4*)(ss + c4);
    float4 sh = *(const float4*)(ss + 256 + c4);
    ushort4 yv = *(const ushort4*)(y + (size_t)node * 256 + c4);
    float f = fold ? norm_src[node] : 1.0f;
    ushort4 o;
    o.x = f2bf(fmaxf(0.f, bf2f(yv.x) * sc.x + sh.x) * f);
    o.y = f2bf(fmaxf(0.f, bf2f(yv.y) * sc.y + sh.y) * f);
    o.z = f2bf(fmaxf(0.f, bf2f(yv.z) * sc.z + sh.z) * f);
    o.w = f2bf(fmaxf(0.f, bf2f(yv.w) * sc.w + sh.w) * f);
    *(ushort4*)(out + (size_t)node * 256 + c4) = o;
}

// ---------------- launch ----------------
extern "C" void kernel_launch(void* const* d_in, const int* in_sizes, int n_in,
                              void* d_out, int out_size, void* d_ws, size_t ws_size,
                              hipStream_t stream) {
    const float* x   = (const float*)d_in[0];
    const int* src   = (const int*)d_in[1];
    const int* dst   = (const int*)d_in[2];
    const float* Ws_[3]    = {(const float*)d_in[3], (const float*)d_in[7],  (const float*)d_in[11]};
    const float* gs_[3]    = {(const float*)d_in[5], (const float*)d_in[9],  (const float*)d_in[13]};
    const float* betas_[3] = {(const float*)d_in[6], (const float*)d_in[10], (const float*)d_in[14]};
    const float* fcW = (const float*)d_in[15];
    const float* fcb = (const float*)d_in[16];
    float* out = (float*)d_out;

    const int N = in_sizes[0] / C_IN;
    const int E = in_sizes[1];
    const int Npad = ((N + 127) / 128) * 128;
    const int nScanBlocks = (N + 1023) / 1024;
    const int epc = (E + ECHUNK - 1) / ECHUNK;
    const int bpc = (epc + 255) / 256;
    const int gemm_rows = Npad / 128;
    const int chunk = (gemm_rows + 7) / 8;

    char* ws = (char*)d_ws;
    size_t o = 0;
    auto alloc = [&](size_t bytes) { size_t p = o; o = (o + bytes + 511) & ~(size_t)511; return p; };
    float* norm_src = (float*)(ws + alloc((size_t)N * 4));
    int* cnt_in     = (int*)(ws + alloc((size_t)N * 4));
    float* norm_dst = (float*)(ws + alloc((size_t)N * 4));
    int* row_ptr    = (int*)(ws + alloc((size_t)(N + 1) * 4));
    int* block_sums = (int*)(ws + alloc((size_t)(nScanBlocks + 1) * 4));
    int* csr_src    = (int*)(ws + alloc((size_t)E * 4));
    unsigned short* rank = (unsigned short*)(ws + alloc((size_t)E * 2));
    int* part_src   = (int*)(ws + alloc((size_t)ECHUNK * NPAD2 * 4));
    int* part_dst   = (int*)(ws + alloc((size_t)ECHUNK * NPAD2 * 4));
    float* statsPart= (float*)(ws + alloc((size_t)gemm_rows * 2 * 256 * 4));
    float* part2    = (float*)(ws + alloc(8 * 512 * 4));
    float* ss       = (float*)(ws + alloc(512 * 4));
    unsigned short* Wt[3];
    Wt[0] = (unsigned short*)(ws + alloc(256 * 256 * 2));
    Wt[1] = (unsigned short*)(ws + alloc(256 * 256 * 2));
    Wt[2] = (unsigned short*)(ws + alloc(256 * 256 * 2));
    unsigned short* Wtfc = (unsigned short*)(ws + alloc(128 * 256 * 2));
    unsigned short* hbuf   = (unsigned short*)(ws + alloc((size_t)Npad * 256 * 2));
    unsigned short* aggbuf = (unsigned short*)(ws + alloc((size_t)Npad * 256 * 2));
    unsigned short* ybuf   = (unsigned short*)(ws + alloc((size_t)Npad * 256 * 2));
    (void)ws_size; (void)n_in; (void)out_size;

    // graph prep: no global atomics anywhere
    hist_pass<<<NCHUNK * ECHUNK, 256, 0, stream>>>(src, dst, part_src, part_dst, rank, E, epc);
    reduce_scan<<<(N + 255) / 256, 256, 0, stream>>>(part_src, part_dst, norm_src, cnt_in, N);
    scan_blocks<<<nScanBlocks, 256, 0, stream>>>(cnt_in, norm_src, norm_dst, row_ptr, block_sums, N);
    scan_add<<<(N + 255) / 256, 256, 0, stream>>>(row_ptr, block_sums, N, E, nScanBlocks);
    csr_scatter<<<ECHUNK * bpc, 256, 0, stream>>>(src, dst, rank, row_ptr, part_dst, csr_src, E, epc, bpc);

    cvt_w_all<<<(3 * 65536 + 128 * 256 + 255) / 256, 256, 0, stream>>>(
        Ws_[0], Ws_[1], Ws_[2], fcW, Wt[0], Wt[1], Wt[2], Wtfc);

    int nb64 = (N * 64 + 255) / 256;
    cvt_x<<<nb64, 256, 0, stream>>>(x, norm_src, hbuf, N);

    int agg_blocks = (N + 3) / 4;
    float invN = 1.0f / (float)N;

    for (int layer = 0; layer < 3; ++layer) {
        if (layer == 0)
            aggregate_bf16<<<agg_blocks, 256, 0, stream>>>(hbuf, csr_src, row_ptr, norm_dst, aggbuf, N);
        else
            aggregate_bn_fused<<<agg_blocks, 256, 0, stream>>>(ybuf, ss, norm_src, csr_src, row_ptr,
                                                               norm_dst, aggbuf, N);
        gemm_mfma<<<dim3(gemm_rows, 2), 256, 0, stream>>>(aggbuf, Wt[layer], nullptr, nullptr, ybuf,
                                                          statsPart, N, C_HID);
        bn_reduce<<<8, 512, 0, stream>>>(statsPart, part2, gemm_rows, chunk);
        bn_params<<<1, 256, 0, stream>>>(part2, gs_[layer], betas_[layer], ss, invN);
    }
    // last layer BN applied standalone (no next aggregate to fuse into)
    bn_relu_cvt<<<nb64, 256, 0, stream>>>(ybuf, ss, norm_src, hbuf, N, 0);
    gemm_mfma<<<dim3(gemm_rows, 1), 256, 0, stream>>>(hbuf, Wtfc, fcb, out, nullptr, nullptr, N, C_OUT);
}

// Round 13
// 388.036 us; speedup vs baseline: 1.6525x; 1.0105x over previous
//
#include <hip/hip_runtime.h>
#include <hip/hip_bf16.h>

#define C_IN 256
#define C_HID 256
#define C_OUT 64
#define EPSV 1e-5f

// graph-prep histogram geometry
#define NCHUNK 8
#define NCHUNK_LOG 3
#define RANGE 6272           // 8*6272 = 50176 >= N
#define NPAD2 (NCHUNK * RANGE)
#define ECHUNK 64

typedef __bf16 bfv8 __attribute__((ext_vector_type(8)));
typedef float f32x4 __attribute__((ext_vector_type(4)));
typedef unsigned short ushort8v __attribute__((ext_vector_type(8)));

__device__ __forceinline__ float bf2f(unsigned short u) {
    return __uint_as_float(((unsigned int)u) << 16);
}
__device__ __forceinline__ unsigned short f2bf(float f) {
    unsigned int u = __float_as_uint(f);
    unsigned int r = (u + 0x7fffu + ((u >> 16) & 1u)) >> 16;
    return (unsigned short)r;
}

__device__ __forceinline__ void gload_lds16(const void* g, void* l) {
    __builtin_amdgcn_global_load_lds(
        (const __attribute__((address_space(1))) unsigned int*)g,
        (__attribute__((address_space(3))) unsigned int*)l, 16, 0, 0);
}

// ---------------- pass 1: packed LDS histograms (src=low16, dst=high16) + per-edge rank ----------------
__global__ __launch_bounds__(256) void hist_pass(const int* __restrict__ src, const int* __restrict__ dst,
        unsigned int* __restrict__ partpk, unsigned short* __restrict__ rank,
        int E, int epc) {
    __shared__ unsigned int hist[RANGE];   // low16: src count, high16: dst count
    int nc = blockIdx.x & (NCHUNK - 1);
    int ec = blockIdx.x >> NCHUNK_LOG;
    int vbase = nc * RANGE;
    for (int i = threadIdx.x; i < RANGE; i += 256) hist[i] = 0;
    __syncthreads();
    int e0 = ec * epc, e1 = min(e0 + epc, E);
    for (int e = e0 + threadIdx.x; e < e1; e += 256) {
        unsigned rs = (unsigned)(src[e] - vbase);
        unsigned rd = (unsigned)(dst[e] - vbase);
        if (rs < RANGE) atomicAdd(&hist[rs], 1u);
        if (rd < RANGE) {
            unsigned old = atomicAdd(&hist[rd], 0x10000u);
            rank[e] = (unsigned short)(old >> 16);   // rank within (ec, dst-node)
        }
    }
    __syncthreads();
    size_t base = (size_t)ec * NPAD2 + vbase;
    for (int i = threadIdx.x; i < RANGE; i += 256)
        partpk[base + i] = hist[i];
}

// ---------------- reduce partials: deg_out, cnt_in, per-chunk exclusive offsets (u16) ----------------
__global__ void reduce_scan(const unsigned int* __restrict__ partpk, unsigned short* __restrict__ chunk_off,
                            float* __restrict__ deg_out, int* __restrict__ cnt_in, int N) {
    int v = blockIdx.x * 256 + threadIdx.x;
    if (v >= N) return;
    int ssum = 0, run = 0;
    #pragma unroll 8
    for (int ec = 0; ec < ECHUNK; ++ec) {
        unsigned p = partpk[(size_t)ec * NPAD2 + v];
        ssum += (int)(p & 0xFFFFu);
        chunk_off[(size_t)ec * NPAD2 + v] = (unsigned short)run;
        run += (int)(p >> 16);
    }
    deg_out[v] = (float)ssum;
    cnt_in[v] = run;
}

// ---------------- scan phase 1 + norms ----------------
__global__ __launch_bounds__(256) void scan_blocks(const int* __restrict__ cnt_in,
        float* __restrict__ deg_out_to_norm_src, float* __restrict__ norm_dst,
        int* __restrict__ row_ptr, int* __restrict__ block_sums, int N) {
    __shared__ int wave_sums[4];
    int b = blockIdx.x;
    int tid = threadIdx.x;
    int lane = tid & 63, w = tid >> 6;
    int idx = b * 1024 + tid * 4;
    int4 v = {0, 0, 0, 0};
    if (idx + 3 < N) v = *(const int4*)(cnt_in + idx);
    else {
        if (idx + 0 < N) v.x = cnt_in[idx + 0];
        if (idx + 1 < N) v.y = cnt_in[idx + 1];
        if (idx + 2 < N) v.z = cnt_in[idx + 2];
        if (idx + 3 < N) v.w = cnt_in[idx + 3];
    }
    int tsum = v.x + v.y + v.z + v.w;
    int s = tsum;
    #pragma unroll
    for (int off = 1; off < 64; off <<= 1) {
        int t = __shfl_up(s, off, 64);
        if (lane >= off) s += t;
    }
    if (lane == 63) wave_sums[w] = s;
    __syncthreads();
    int woff = 0;
    for (int i = 0; i < w; ++i) woff += wave_sums[i];
    int excl = woff + s - tsum;
    int p0 = excl, p1 = p0 + v.x, p2 = p1 + v.y, p3 = p2 + v.z;
    if (idx + 3 < N) {
        *(int4*)(row_ptr + idx) = make_int4(p0, p1, p2, p3);
        float4 d = *(const float4*)(deg_out_to_norm_src + idx);
        float4 ns, nd;
        ns.x = d.x > 0.f ? rsqrtf(d.x) : 0.f;
        ns.y = d.y > 0.f ? rsqrtf(d.y) : 0.f;
        ns.z = d.z > 0.f ? rsqrtf(d.z) : 0.f;
        ns.w = d.w > 0.f ? rsqrtf(d.w) : 0.f;
        nd.x = v.x > 0 ? rsqrtf((float)v.x) : 0.f;
        nd.y = v.y > 0 ? rsqrtf((float)v.y) : 0.f;
        nd.z = v.z > 0 ? rsqrtf((float)v.z) : 0.f;
        nd.w = v.w > 0 ? rsqrtf((float)v.w) : 0.f;
        *(float4*)(deg_out_to_norm_src + idx) = ns;
        *(float4*)(norm_dst + idx) = nd;
    } else {
        int ps[4] = {p0, p1, p2, p3};
        int cs[4] = {v.x, v.y, v.z, v.w};
        for (int j = 0; j < 4; ++j) {
            int i2 = idx + j;
            if (i2 < N) {
                row_ptr[i2] = ps[j];
                float d = deg_out_to_norm_src[i2];
                deg_out_to_norm_src[i2] = d > 0.f ? rsqrtf(d) : 0.f;
                norm_dst[i2] = cs[j] > 0 ? rsqrtf((float)cs[j]) : 0.f;
            }
        }
    }
    if (tid == 255) block_sums[b] = woff + s;
}

// ---------------- scan phase 2+3 merged ----------------
__global__ void scan_add(int* __restrict__ row_ptr, const int* __restrict__ bs, int N, int E, int nb) {
    __shared__ int soff[256];
    int tid = threadIdx.x;
    if (tid < 64) {
        int carry = 0;
        for (int base = 0; base < nb; base += 64) {
            int i = base + tid;
            int v = (i < nb) ? bs[i] : 0;
            int s = v;
            #pragma unroll
            for (int off = 1; off < 64; off <<= 1) {
                int t = __shfl_up(s, off, 64);
                if (tid >= off) s += t;
            }
            if (i < nb && i < 256) soff[i] = carry + s - v;
            carry += __shfl(s, 63, 64);
        }
    }
    __syncthreads();
    int i = blockIdx.x * blockDim.x + tid;
    if (i == 0) row_ptr[N] = E;
    if (i < N) row_ptr[i] += soff[i >> 10];
}

// ---------------- pass 2: flat CSR scatter using precomputed ranks ----------------
__global__ __launch_bounds__(256) void csr_scatter(const int* __restrict__ src, const int* __restrict__ dst,
        const unsigned short* __restrict__ rank, const int* __restrict__ row_ptr,
        const unsigned short* __restrict__ chunk_off, int* __restrict__ csr_src, int E, int epc, int bpc) {
    int ec = blockIdx.x / bpc;
    int off = (blockIdx.x - ec * bpc) * 256 + threadIdx.x;
    if (off >= epc) return;
    int e = ec * epc + off;
    if (e >= E) return;
    int d = dst[e];
    int pos = row_ptr[d] + (int)chunk_off[(size_t)ec * NPAD2 + d] + (int)rank[e];
    csr_src[pos] = src[e];
}

// ---------------- conversions ----------------
__global__ void cvt_x(const float* __restrict__ x, const float* __restrict__ norm_src,
                      unsigned short* __restrict__ hs, int N) {
    int i = blockIdx.x * blockDim.x + threadIdx.x;
    if (i >= N * 64) return;
    int node = i >> 6;
    int c4 = (i & 63) << 2;
    float4 v = *(const float4*)(x + (size_t)node * 256 + c4);
    float f = norm_src[node];
    ushort4 o;
    o.x = f2bf(v.x * f); o.y = f2bf(v.y * f); o.z = f2bf(v.z * f); o.w = f2bf(v.w * f);
    *(ushort4*)(hs + (size_t)node * 256 + c4) = o;
}

__global__ void cvt_w_all(const float* __restrict__ W0, const float* __restrict__ W1,
                          const float* __restrict__ W2, const float* __restrict__ Wfc,
                          unsigned short* __restrict__ T0, unsigned short* __restrict__ T1,
                          unsigned short* __restrict__ T2, unsigned short* __restrict__ Tfc) {
    int idx = blockIdx.x * 256 + threadIdx.x;
    if (idx < 3 * 65536) {
        int l = idx >> 16, r = idx & 65535;
        const float* W = (l == 0) ? W0 : (l == 1) ? W1 : W2;
        unsigned short* T = (l == 0) ? T0 : (l == 1) ? T1 : T2;
        int n = r >> 8, k = r & 255;
        T[r] = f2bf(W[(size_t)k * 256 + n]);
    } else {
        int r = idx - 3 * 65536;
        if (r < 128 * 256) {
            int n = r >> 8, k = r & 255;
            Tfc[r] = f2bf((n < 64) ? Wfc[(size_t)k * 64 + n] : 0.f);
        }
    }
}

// ---------------- aggregation (plain): input already BN'd/folded ----------------
__global__ __launch_bounds__(256) void aggregate_bf16(const unsigned short* __restrict__ h,
                          const int* __restrict__ csr_src, const int* __restrict__ row_ptr,
                          const float* __restrict__ norm_dst,
                          unsigned short* __restrict__ out, int N) {
    int node = (blockIdx.x * blockDim.x + threadIdx.x) >> 6;
    int lane = threadIdx.x & 63;
    if (node >= N) return;
    int beg = row_ptr[node], end = row_ptr[node + 1];
    int half = lane >> 5;
    int cg = (lane & 31) << 3;
    float acc[8] = {};
    int e = beg;
    for (; e + 7 < end; e += 8) {
        int i0 = csr_src[e + half];
        int i1 = csr_src[e + 2 + half];
        int i2 = csr_src[e + 4 + half];
        int i3 = csr_src[e + 6 + half];
        ushort8v v0 = *(const ushort8v*)(h + (size_t)i0 * 256 + cg);
        ushort8v v1 = *(const ushort8v*)(h + (size_t)i1 * 256 + cg);
        ushort8v v2 = *(const ushort8v*)(h + (size_t)i2 * 256 + cg);
        ushort8v v3 = *(const ushort8v*)(h + (size_t)i3 * 256 + cg);
        #pragma unroll
        for (int j = 0; j < 8; ++j)
            acc[j] += (bf2f(v0[j]) + bf2f(v1[j])) + (bf2f(v2[j]) + bf2f(v3[j]));
    }
    for (; e + 1 < end; e += 2) {
        int i0 = csr_src[e + half];
        ushort8v v0 = *(const ushort8v*)(h + (size_t)i0 * 256 + cg);
        #pragma unroll
        for (int j = 0; j < 8; ++j) acc[j] += bf2f(v0[j]);
    }
    if (e < end && half == 0) {
        int i0 = csr_src[e];
        ushort8v v0 = *(const ushort8v*)(h + (size_t)i0 * 256 + cg);
        #pragma unroll
        for (int j = 0; j < 8; ++j) acc[j] += bf2f(v0[j]);
    }
    #pragma unroll
    for (int j = 0; j < 8; ++j) acc[j] += __shfl_xor(acc[j], 32, 64);
    if (half == 0) {
        float nd = norm_dst[node];
        ushort8v o;
        #pragma unroll
        for (int j = 0; j < 8; ++j) o[j] = f2bf(acc[j] * nd);
        *(ushort8v*)(out + (size_t)node * 256 + cg) = o;
    }
}

// ---------------- aggregation with fused BN+ReLU+norm_src (reads raw gemm output) ----------------
__global__ __launch_bounds__(256) void aggregate_bn_fused(const unsigned short* __restrict__ y,
                          const float* __restrict__ ss, const float* __restrict__ norm_src,
                          const int* __restrict__ csr_src, const int* __restrict__ row_ptr,
                          const float* __restrict__ norm_dst,
                          unsigned short* __restrict__ out, int N) {
    int node = (blockIdx.x * blockDim.x + threadIdx.x) >> 6;
    int lane = threadIdx.x & 63;
    if (node >= N) return;
    int beg = row_ptr[node], end = row_ptr[node + 1];
    int half = lane >> 5;
    int cg = (lane & 31) << 3;
    float scv[8], shv[8];
    {
        float4 a = *(const float4*)(ss + cg);
        float4 b = *(const float4*)(ss + cg + 4);
        float4 c = *(const float4*)(ss + 256 + cg);
        float4 d = *(const float4*)(ss + 256 + cg + 4);
        scv[0]=a.x; scv[1]=a.y; scv[2]=a.z; scv[3]=a.w; scv[4]=b.x; scv[5]=b.y; scv[6]=b.z; scv[7]=b.w;
        shv[0]=c.x; shv[1]=c.y; shv[2]=c.z; shv[3]=c.w; shv[4]=d.x; shv[5]=d.y; shv[6]=d.z; shv[7]=d.w;
    }
    float acc[8] = {};
    int e = beg;
    for (; e + 7 < end; e += 8) {
        int i0 = csr_src[e + half];
        int i1 = csr_src[e + 2 + half];
        int i2 = csr_src[e + 4 + half];
        int i3 = csr_src[e + 6 + half];
        float n0 = norm_src[i0], n1 = norm_src[i1], n2 = norm_src[i2], n3 = norm_src[i3];
        ushort8v v0 = *(const ushort8v*)(y + (size_t)i0 * 256 + cg);
        ushort8v v1 = *(const ushort8v*)(y + (size_t)i1 * 256 + cg);
        ushort8v v2 = *(const ushort8v*)(y + (size_t)i2 * 256 + cg);
        ushort8v v3 = *(const ushort8v*)(y + (size_t)i3 * 256 + cg);
        #pragma unroll
        for (int j = 0; j < 8; ++j) {
            acc[j] += n0 * fmaxf(0.f, bf2f(v0[j]) * scv[j] + shv[j]);
            acc[j] += n1 * fmaxf(0.f, bf2f(v1[j]) * scv[j] + shv[j]);
            acc[j] += n2 * fmaxf(0.f, bf2f(v2[j]) * scv[j] + shv[j]);
            acc[j] += n3 * fmaxf(0.f, bf2f(v3[j]) * scv[j] + shv[j]);
        }
    }
    for (; e + 1 < end; e += 2) {
        int i0 = csr_src[e + half];
        float n0 = norm_src[i0];
        ushort8v v0 = *(const ushort8v*)(y + (size_t)i0 * 256 + cg);
        #pragma unroll
        for (int j = 0; j < 8; ++j)
            acc[j] += n0 * fmaxf(0.f, bf2f(v0[j]) * scv[j] + shv[j]);
    }
    if (e < end && half == 0) {
        int i0 = csr_src[e];
        float n0 = norm_src[i0];
        ushort8v v0 = *(const ushort8v*)(y + (size_t)i0 * 256 + cg);
        #pragma unroll
        for (int j = 0; j < 8; ++j)
            acc[j] += n0 * fmaxf(0.f, bf2f(v0[j]) * scv[j] + shv[j]);
    }
    #pragma unroll
    for (int j = 0; j < 8; ++j) acc[j] += __shfl_xor(acc[j], 32, 64);
    if (half == 0) {
        float nd = norm_dst[node];
        ushort8v o;
        #pragma unroll
        for (int j = 0; j < 8; ++j) o[j] = f2bf(acc[j] * nd);
        *(ushort8v*)(out + (size_t)node * 256 + cg) = o;
    }
}

// ---------------- MFMA GEMM: 2-phase dbuf staging, LDS-relayout C-write, stats partials ----------------
__global__ __launch_bounds__(256) void gemm_mfma(const unsigned short* __restrict__ A,
                          const unsigned short* __restrict__ Bt,
                          const float* __restrict__ bias, float* __restrict__ Cf,
                          unsigned short* __restrict__ Cbf,
                          float* __restrict__ statsPart, int M, int ncols) {
    __shared__ char smem[32768];          // [A dbuf 16KB][B dbuf 16KB]; reused as 4x8KB C-tiles
    __shared__ float sstat[256];
    int tid = threadIdx.x;
    int wid = tid >> 6, lane = tid & 63;
    int wm = wid >> 1, wn = wid & 1;
    size_t row0 = (size_t)blockIdx.x * 128;
    int n0 = blockIdx.y * 128;
    f32x4 acc[4][4] = {};
    const char* Ab = (const char*)(A + row0 * 256);
    const char* Bb = (const char*)(Bt + (size_t)n0 * 256);
    char* AsB = smem;
    char* BsB = smem + 16384;
    if (tid < 256) sstat[tid] = 0.f;

    auto STAGE = [&](int buf, int k0) {
        #pragma unroll
        for (int j = 0; j < 2; ++j) {
            int boff = (wid * 2 + j) * 1024 + lane * 16;
            int row = boff >> 6, col = boff & 63;
            gload_lds16(Ab + (size_t)row * 512 + (size_t)k0 * 2 + col, AsB + buf * 8192 + (wid * 2 + j) * 1024);
            gload_lds16(Bb + (size_t)row * 512 + (size_t)k0 * 2 + col, BsB + buf * 8192 + (wid * 2 + j) * 1024);
        }
    };

    STAGE(0, 0);
    __syncthreads();
    for (int t = 0; t < 8; ++t) {
        int cur = t & 1;
        if (t < 7) STAGE(cur ^ 1, (t + 1) * 32);
        const char* Ac = AsB + cur * 8192;
        const char* Bc = BsB + cur * 8192;
        bfv8 af[4], bfr[4];
        #pragma unroll
        for (int m = 0; m < 4; ++m)
            af[m] = *(const bfv8*)(Ac + ((wm * 64 + m * 16 + (lane & 15)) * 64 + (lane >> 4) * 16));
        #pragma unroll
        for (int n = 0; n < 4; ++n)
            bfr[n] = *(const bfv8*)(Bc + ((wn * 64 + n * 16 + (lane & 15)) * 64 + (lane >> 4) * 16));
        #pragma unroll
        for (int m = 0; m < 4; ++m)
            #pragma unroll
            for (int n = 0; n < 4; ++n)
                acc[m][n] = __builtin_amdgcn_mfma_f32_16x16x32_bf16(af[m], bfr[n], acc[m][n], 0, 0, 0);
        __syncthreads();
    }

    if (statsPart) {
        #pragma unroll
        for (int n = 0; n < 4; ++n) {
            float s1 = 0.f, s2 = 0.f;
            #pragma unroll
            for (int m = 0; m < 4; ++m) {
                size_t rbase = row0 + wm * 64 + m * 16 + ((lane >> 4) << 2);
                #pragma unroll
                for (int r = 0; r < 4; ++r) {
                    float v = ((rbase + r) < (size_t)M) ? acc[m][n][r] : 0.f;
                    s1 += v;
                    s2 += v * v;
                }
            }
            s1 += __shfl_xor(s1, 16, 64); s1 += __shfl_xor(s1, 32, 64);
            s2 += __shfl_xor(s2, 16, 64); s2 += __shfl_xor(s2, 32, 64);
            if (lane < 16) {
                int lc = wn * 64 + n * 16 + lane;
                atomicAdd(&sstat[lc], s1);
                atomicAdd(&sstat[128 + lc], s2);
            }
        }
        __syncthreads();
        if (tid < 256)
            statsPart[((size_t)blockIdx.x * gridDim.y + blockIdx.y) * 256 + tid] = sstat[tid];
    }

    if (Cbf) {
        char* creg = smem + wid * 8192;
        #pragma unroll
        for (int m = 0; m < 4; ++m)
            #pragma unroll
            for (int n = 0; n < 4; ++n) {
                int col = n * 16 + (lane & 15);
                #pragma unroll
                for (int r = 0; r < 4; ++r) {
                    int row = m * 16 + ((lane >> 4) << 2) + r;
                    *(unsigned short*)(creg + row * 128 + col * 2) = f2bf(acc[m][n][r]);
                }
            }
        #pragma unroll
        for (int p = 0; p < 8; ++p) {
            int row = p * 8 + (lane >> 3);
            int slot = lane & 7;
            size_t grow = row0 + wm * 64 + row;
            if (grow < (size_t)M)
                *(ushort8v*)(Cbf + grow * ncols + n0 + wn * 64 + slot * 8) =
                    *(const ushort8v*)(creg + row * 128 + slot * 16);
        }
    } else {
        #pragma unroll
        for (int n = 0; n < 4; ++n) {
            int col = n0 + wn * 64 + n * 16 + (lane & 15);
            if (col < ncols) {
                float b = bias ? bias[col] : 0.0f;
                #pragma unroll
                for (int m = 0; m < 4; ++m) {
                    size_t rbase = row0 + wm * 64 + m * 16 + ((lane >> 4) << 2);
                    #pragma unroll
                    for (int r = 0; r < 4; ++r) {
                        size_t row = rbase + r;
                        if (row < (size_t)M)
                            Cf[row * ncols + col] = acc[m][n][r] + b;
                    }
                }
            }
        }
    }
}

// ---------------- BN stats reduction (two-stage: 8 blocks then 1 block) ----------------
__global__ void bn_reduce(const float* __restrict__ part, float* __restrict__ part2, int nbx, int chunk) {
    int g = blockIdx.x, t = threadIdx.x;     // grid(8), 512 threads
    int b0 = g * chunk, b1 = min(b0 + chunk, nbx);
    int by, elem;
    if (t < 256) { by = t >> 7; elem = t & 127; }
    else { int c = t - 256; by = c >> 7; elem = 128 + (c & 127); }
    float s = 0.f;
    for (int bx = b0; bx < b1; ++bx)
        s += part[((size_t)bx * 2 + by) * 256 + elem];
    part2[g * 512 + t] = s;
}

__global__ void bn_params(const float* __restrict__ part2, const float* __restrict__ g,
                          const float* __restrict__ beta, float* __restrict__ ss, float invN) {
    int c = threadIdx.x;   // 256
    float s1 = 0.f, s2 = 0.f;
    #pragma unroll
    for (int k = 0; k < 8; ++k) { s1 += part2[k * 512 + c]; s2 += part2[k * 512 + 256 + c]; }
    float m = s1 * invN;
    float var = s2 * invN - m * m;
    float sc = g[c] * rsqrtf(var + EPSV);
    ss[c] = sc;
    ss[256 + c] = beta[c] - m * sc;
}

// ---------------- BN apply (bf16 in, bf16 out) — last layer only ----------------
__global__ void bn_relu_cvt(const unsigned short* __restrict__ y, const float* __restrict__ ss,
                            const float* __restrict__ norm_src, unsigned short* __restrict__ out,
                            int N, int fold) {
    int i = blockIdx.x * blockDim.x + threadIdx.x;
    if (i >= N * 64) return;
    int node = i >> 6;
    int c4 = (i & 63) << 2;
    float4 sc = *(const float4*)(ss + c4);
    float4 sh = *(const float4*)(ss + 256 + c4);
    ushort4 yv = *(const ushort4*)(y + (size_t)node * 256 + c4);
    float f = fold ? norm_src[node] : 1.0f;
    ushort4 o;
    o.x = f2bf(fmaxf(0.f, bf2f(yv.x) * sc.x + sh.x) * f);
    o.y = f2bf(fmaxf(0.f, bf2f(yv.y) * sc.y + sh.y) * f);
    o.z = f2bf(fmaxf(0.f, bf2f(yv.z) * sc.z + sh.z) * f);
    o.w = f2bf(fmaxf(0.f, bf2f(yv.w) * sc.w + sh.w) * f);
    *(ushort4*)(out + (size_t)node * 256 + c4) = o;
}

// ---------------- launch ----------------
extern "C" void kernel_launch(void* const* d_in, const int* in_sizes, int n_in,
                              void* d_out, int out_size, void* d_ws, size_t ws_size,
                              hipStream_t stream) {
    const float* x   = (const float*)d_in[0];
    const int* src   = (const int*)d_in[1];
    const int* dst   = (const int*)d_in[2];
    const float* Ws_[3]    = {(const float*)d_in[3], (const float*)d_in[7],  (const float*)d_in[11]};
    const float* gs_[3]    = {(const float*)d_in[5], (const float*)d_in[9],  (const float*)d_in[13]};
    const float* betas_[3] = {(const float*)d_in[6], (const float*)d_in[10], (const float*)d_in[14]};
    const float* fcW = (const float*)d_in[15];
    const float* fcb = (const float*)d_in[16];
    float* out = (float*)d_out;

    const int N = in_sizes[0] / C_IN;
    const int E = in_sizes[1];
    const int Npad = ((N + 127) / 128) * 128;
    const int nScanBlocks = (N + 1023) / 1024;
    const int epc = (E + ECHUNK - 1) / ECHUNK;
    const int bpc = (epc + 255) / 256;
    const int gemm_rows = Npad / 128;
    const int chunk = (gemm_rows + 7) / 8;

    char* ws = (char*)d_ws;
    size_t o = 0;
    auto alloc = [&](size_t bytes) { size_t p = o; o = (o + bytes + 511) & ~(size_t)511; return p; };
    float* norm_src = (float*)(ws + alloc((size_t)N * 4));
    int* cnt_in     = (int*)(ws + alloc((size_t)N * 4));
    float* norm_dst = (float*)(ws + alloc((size_t)N * 4));
    int* row_ptr    = (int*)(ws + alloc((size_t)(N + 1) * 4));
    int* block_sums = (int*)(ws + alloc((size_t)(nScanBlocks + 1) * 4));
    int* csr_src    = (int*)(ws + alloc((size_t)E * 4));
    unsigned short* rank = (unsigned short*)(ws + alloc((size_t)E * 2));
    unsigned int* partpk = (unsigned int*)(ws + alloc((size_t)ECHUNK * NPAD2 * 4));
    unsigned short* chunk_off = (unsigned short*)(ws + alloc((size_t)ECHUNK * NPAD2 * 2));
    float* statsPart= (float*)(ws + alloc((size_t)gemm_rows * 2 * 256 * 4));
    float* part2    = (float*)(ws + alloc(8 * 512 * 4));
    float* ss       = (float*)(ws + alloc(512 * 4));
    unsigned short* Wt[3];
    Wt[0] = (unsigned short*)(ws + alloc(256 * 256 * 2));
    Wt[1] = (unsigned short*)(ws + alloc(256 * 256 * 2));
    Wt[2] = (unsigned short*)(ws + alloc(256 * 256 * 2));
    unsigned short* Wtfc = (unsigned short*)(ws + alloc(128 * 256 * 2));
    unsigned short* hbuf   = (unsigned short*)(ws + alloc((size_t)Npad * 256 * 2));
    unsigned short* aggbuf = (unsigned short*)(ws + alloc((size_t)Npad * 256 * 2));
    unsigned short* ybuf   = (unsigned short*)(ws + alloc((size_t)Npad * 256 * 2));
    (void)ws_size; (void)n_in; (void)out_size;

    // graph prep: no global atomics anywhere
    hist_pass<<<NCHUNK * ECHUNK, 256, 0, stream>>>(src, dst, partpk, rank, E, epc);
    reduce_scan<<<(N + 255) / 256, 256, 0, stream>>>(partpk, chunk_off, norm_src, cnt_in, N);
    scan_blocks<<<nScanBlocks, 256, 0, stream>>>(cnt_in, norm_src, norm_dst, row_ptr, block_sums, N);
    scan_add<<<(N + 255) / 256, 256, 0, stream>>>(row_ptr, block_sums, N, E, nScanBlocks);
    csr_scatter<<<ECHUNK * bpc, 256, 0, stream>>>(src, dst, rank, row_ptr, chunk_off, csr_src, E, epc, bpc);

    cvt_w_all<<<(3 * 65536 + 128 * 256 + 255) / 256, 256, 0, stream>>>(
        Ws_[0], Ws_[1], Ws_[2], fcW, Wt[0], Wt[1], Wt[2], Wtfc);

    int nb64 = (N * 64 + 255) / 256;
    cvt_x<<<nb64, 256, 0, stream>>>(x, norm_src, hbuf, N);

    int agg_blocks = (N + 3) / 4;
    float invN = 1.0f / (float)N;

    for (int layer = 0; layer < 3; ++layer) {
        if (layer == 0)
            aggregate_bf16<<<agg_blocks, 256, 0, stream>>>(hbuf, csr_src, row_ptr, norm_dst, aggbuf, N);
        else
            aggregate_bn_fused<<<agg_blocks, 256, 0, stream>>>(ybuf, ss, norm_src, csr_src, row_ptr,
                                                               norm_dst, aggbuf, N);
        gemm_mfma<<<dim3(gemm_rows, 2), 256, 0, stream>>>(aggbuf, Wt[layer], nullptr, nullptr, ybuf,
                                                          statsPart, N, C_HID);
        bn_reduce<<<8, 512, 0, stream>>>(statsPart, part2, gemm_rows, chunk);
        bn_params<<<1, 256, 0, stream>>>(part2, gs_[layer], betas_[layer], ss, invN);
    }
    // last layer BN applied standalone (no next aggregate to fuse into)
    bn_relu_cvt<<<nb64, 256, 0, stream>>>(ybuf, ss, norm_src, hbuf, N, 0);
    gemm_mfma<<<dim3(gemm_rows, 1), 256, 0, stream>>>(hbuf, Wtfc, fcb, out, nullptr, nullptr, N, C_OUT);
}

// Round 14
// 384.162 us; speedup vs baseline: 1.6692x; 1.0101x over previous
//
#include <hip/hip_runtime.h>
#include <hip/hip_bf16.h>

#define C_IN 256
#define C_HID 256
#define C_OUT 64
#define EPSV 1e-5f

// graph-prep histogram geometry
#define NCHUNK 8
#define NCHUNK_LOG 3
#define RANGE 6272           // 8*6272 = 50176 >= N
#define NPAD2 (NCHUNK * RANGE)
#define ECHUNK 64

typedef __bf16 bfv8 __attribute__((ext_vector_type(8)));
typedef float f32x4 __attribute__((ext_vector_type(4)));
typedef unsigned short ushort8v __attribute__((ext_vector_type(8)));

__device__ __forceinline__ float bf2f(unsigned short u) {
    return __uint_as_float(((unsigned int)u) << 16);
}
__device__ __forceinline__ unsigned short f2bf(float f) {
    unsigned int u = __float_as_uint(f);
    unsigned int r = (u + 0x7fffu + ((u >> 16) & 1u)) >> 16;
    return (unsigned short)r;
}

__device__ __forceinline__ void gload_lds16(const void* g, void* l) {
    __builtin_amdgcn_global_load_lds(
        (const __attribute__((address_space(1))) unsigned int*)g,
        (__attribute__((address_space(3))) unsigned int*)l, 16, 0, 0);
}

// ---------------- pass 1: packed LDS histograms (src=low16, dst=high16) + per-edge rank ----------------
// int4-vectorized edge stream: 4 edges per thread-iteration
__global__ __launch_bounds__(256) void hist_pass(const int* __restrict__ src, const int* __restrict__ dst,
        unsigned int* __restrict__ partpk, unsigned short* __restrict__ rank,
        int E, int epc) {
    __shared__ unsigned int hist[RANGE];   // low16: src count, high16: dst count
    int nc = blockIdx.x & (NCHUNK - 1);
    int ec = blockIdx.x >> NCHUNK_LOG;
    int vbase = nc * RANGE;
    for (int i = threadIdx.x; i < RANGE; i += 256) hist[i] = 0;
    __syncthreads();
    int e0 = ec * epc, e1 = min(e0 + epc, E);
    for (int e = e0 + threadIdx.x * 4; e < e1; e += 1024) {
        if (e + 3 < e1) {
            int4 s4 = *(const int4*)(src + e);
            int4 d4 = *(const int4*)(dst + e);
            int sv[4] = {s4.x, s4.y, s4.z, s4.w};
            int dv[4] = {d4.x, d4.y, d4.z, d4.w};
            #pragma unroll
            for (int j = 0; j < 4; ++j) {
                unsigned rs = (unsigned)(sv[j] - vbase);
                unsigned rd = (unsigned)(dv[j] - vbase);
                if (rs < RANGE) atomicAdd(&hist[rs], 1u);
                if (rd < RANGE) {
                    unsigned old = atomicAdd(&hist[rd], 0x10000u);
                    rank[e + j] = (unsigned short)(old >> 16);
                }
            }
        } else {
            for (int j = 0; j < 4 && e + j < e1; ++j) {
                unsigned rs = (unsigned)(src[e + j] - vbase);
                unsigned rd = (unsigned)(dst[e + j] - vbase);
                if (rs < RANGE) atomicAdd(&hist[rs], 1u);
                if (rd < RANGE) {
                    unsigned old = atomicAdd(&hist[rd], 0x10000u);
                    rank[e + j] = (unsigned short)(old >> 16);
                }
            }
        }
    }
    __syncthreads();
    size_t base = (size_t)ec * NPAD2 + vbase;
    for (int i = threadIdx.x; i < RANGE; i += 256)
        partpk[base + i] = hist[i];
}

// ---------------- reduce partials: deg_out, cnt_in, per-chunk exclusive offsets (u16) ----------------
__global__ void reduce_scan(const unsigned int* __restrict__ partpk, unsigned short* __restrict__ chunk_off,
                            float* __restrict__ deg_out, int* __restrict__ cnt_in, int N) {
    int v = blockIdx.x * 256 + threadIdx.x;
    if (v >= N) return;
    int ssum = 0, run = 0;
    #pragma unroll 8
    for (int ec = 0; ec < ECHUNK; ++ec) {
        unsigned p = partpk[(size_t)ec * NPAD2 + v];
        ssum += (int)(p & 0xFFFFu);
        chunk_off[(size_t)ec * NPAD2 + v] = (unsigned short)run;
        run += (int)(p >> 16);
    }
    deg_out[v] = (float)ssum;
    cnt_in[v] = run;
}

// ---------------- scan phase 1 + norms ----------------
__global__ __launch_bounds__(256) void scan_blocks(const int* __restrict__ cnt_in,
        float* __restrict__ deg_out_to_norm_src, float* __restrict__ norm_dst,
        int* __restrict__ row_ptr, int* __restrict__ block_sums, int N) {
    __shared__ int wave_sums[4];
    int b = blockIdx.x;
    int tid = threadIdx.x;
    int lane = tid & 63, w = tid >> 6;
    int idx = b * 1024 + tid * 4;
    int4 v = {0, 0, 0, 0};
    if (idx + 3 < N) v = *(const int4*)(cnt_in + idx);
    else {
        if (idx + 0 < N) v.x = cnt_in[idx + 0];
        if (idx + 1 < N) v.y = cnt_in[idx + 1];
        if (idx + 2 < N) v.z = cnt_in[idx + 2];
        if (idx + 3 < N) v.w = cnt_in[idx + 3];
    }
    int tsum = v.x + v.y + v.z + v.w;
    int s = tsum;
    #pragma unroll
    for (int off = 1; off < 64; off <<= 1) {
        int t = __shfl_up(s, off, 64);
        if (lane >= off) s += t;
    }
    if (lane == 63) wave_sums[w] = s;
    __syncthreads();
    int woff = 0;
    for (int i = 0; i < w; ++i) woff += wave_sums[i];
    int excl = woff + s - tsum;
    int p0 = excl, p1 = p0 + v.x, p2 = p1 + v.y, p3 = p2 + v.z;
    if (idx + 3 < N) {
        *(int4*)(row_ptr + idx) = make_int4(p0, p1, p2, p3);
        float4 d = *(const float4*)(deg_out_to_norm_src + idx);
        float4 ns, nd;
        ns.x = d.x > 0.f ? rsqrtf(d.x) : 0.f;
        ns.y = d.y > 0.f ? rsqrtf(d.y) : 0.f;
        ns.z = d.z > 0.f ? rsqrtf(d.z) : 0.f;
        ns.w = d.w > 0.f ? rsqrtf(d.w) : 0.f;
        nd.x = v.x > 0 ? rsqrtf((float)v.x) : 0.f;
        nd.y = v.y > 0 ? rsqrtf((float)v.y) : 0.f;
        nd.z = v.z > 0 ? rsqrtf((float)v.z) : 0.f;
        nd.w = v.w > 0 ? rsqrtf((float)v.w) : 0.f;
        *(float4*)(deg_out_to_norm_src + idx) = ns;
        *(float4*)(norm_dst + idx) = nd;
    } else {
        int ps[4] = {p0, p1, p2, p3};
        int cs[4] = {v.x, v.y, v.z, v.w};
        for (int j = 0; j < 4; ++j) {
            int i2 = idx + j;
            if (i2 < N) {
                row_ptr[i2] = ps[j];
                float d = deg_out_to_norm_src[i2];
                deg_out_to_norm_src[i2] = d > 0.f ? rsqrtf(d) : 0.f;
                norm_dst[i2] = cs[j] > 0 ? rsqrtf((float)cs[j]) : 0.f;
            }
        }
    }
    if (tid == 255) block_sums[b] = woff + s;
}

// ---------------- scan phase 2+3 merged ----------------
__global__ void scan_add(int* __restrict__ row_ptr, const int* __restrict__ bs, int N, int E, int nb) {
    __shared__ int soff[256];
    int tid = threadIdx.x;
    if (tid < 64) {
        int carry = 0;
        for (int base = 0; base < nb; base += 64) {
            int i = base + tid;
            int v = (i < nb) ? bs[i] : 0;
            int s = v;
            #pragma unroll
            for (int off = 1; off < 64; off <<= 1) {
                int t = __shfl_up(s, off, 64);
                if (tid >= off) s += t;
            }
            if (i < nb && i < 256) soff[i] = carry + s - v;
            carry += __shfl(s, 63, 64);
        }
    }
    __syncthreads();
    int i = blockIdx.x * blockDim.x + tid;
    if (i == 0) row_ptr[N] = E;
    if (i < N) row_ptr[i] += soff[i >> 10];
}

// ---------------- pass 2: flat CSR scatter, int4-vectorized ----------------
__global__ __launch_bounds__(256) void csr_scatter(const int* __restrict__ src, const int* __restrict__ dst,
        const unsigned short* __restrict__ rank, const int* __restrict__ row_ptr,
        const unsigned short* __restrict__ chunk_off, int* __restrict__ csr_src, int E, int epc, int bpc) {
    int ec = blockIdx.x / bpc;
    int off4 = ((blockIdx.x - ec * bpc) * 256 + threadIdx.x) * 4;
    if (off4 >= epc) return;
    int e = ec * epc + off4;
    int e1 = min(ec * epc + epc, E);
    if (e >= e1) return;
    const unsigned short* coff = chunk_off + (size_t)ec * NPAD2;
    if (e + 3 < e1) {
        int4 s4 = *(const int4*)(src + e);
        int4 d4 = *(const int4*)(dst + e);
        ushort4 r4 = *(const ushort4*)(rank + e);
        int dv[4] = {d4.x, d4.y, d4.z, d4.w};
        int sv[4] = {s4.x, s4.y, s4.z, s4.w};
        int rv[4] = {r4.x, r4.y, r4.z, r4.w};
        #pragma unroll
        for (int j = 0; j < 4; ++j) {
            int d = dv[j];
            csr_src[row_ptr[d] + (int)coff[d] + rv[j]] = sv[j];
        }
    } else {
        for (int j = 0; j < 4 && e + j < e1; ++j) {
            int d = dst[e + j];
            csr_src[row_ptr[d] + (int)coff[d] + (int)rank[e + j]] = src[e + j];
        }
    }
}

// ---------------- conversions ----------------
__global__ void cvt_x(const float* __restrict__ x, const float* __restrict__ norm_src,
                      unsigned short* __restrict__ hs, int N) {
    int i = blockIdx.x * blockDim.x + threadIdx.x;
    if (i >= N * 64) return;
    int node = i >> 6;
    int c4 = (i & 63) << 2;
    float4 v = *(const float4*)(x + (size_t)node * 256 + c4);
    float f = norm_src[node];
    ushort4 o;
    o.x = f2bf(v.x * f); o.y = f2bf(v.y * f); o.z = f2bf(v.z * f); o.w = f2bf(v.w * f);
    *(ushort4*)(hs + (size_t)node * 256 + c4) = o;
}

__global__ void cvt_w_all(const float* __restrict__ W0, const float* __restrict__ W1,
                          const float* __restrict__ W2, const float* __restrict__ Wfc,
                          unsigned short* __restrict__ T0, unsigned short* __restrict__ T1,
                          unsigned short* __restrict__ T2, unsigned short* __restrict__ Tfc) {
    int idx = blockIdx.x * 256 + threadIdx.x;
    if (idx < 3 * 65536) {
        int l = idx >> 16, r = idx & 65535;
        const float* W = (l == 0) ? W0 : (l == 1) ? W1 : W2;
        unsigned short* T = (l == 0) ? T0 : (l == 1) ? T1 : T2;
        int n = r >> 8, k = r & 255;
        T[r] = f2bf(W[(size_t)k * 256 + n]);
    } else {
        int r = idx - 3 * 65536;
        if (r < 128 * 256) {
            int n = r >> 8, k = r & 255;
            Tfc[r] = f2bf((n < 64) ? Wfc[(size_t)k * 64 + n] : 0.f);
        }
    }
}

// ---------------- shared helper: derive BN scale/shift from part2 into LDS ----------------
__device__ __forceinline__ void bn_derive(const float* __restrict__ part2,
                                          const float* __restrict__ g, const float* __restrict__ beta,
                                          float invN, float* sss /*LDS[512]*/, int tid) {
    if (tid < 256) {
        int c = tid;
        float s1 = 0.f, s2 = 0.f;
        #pragma unroll
        for (int k = 0; k < 8; ++k) { s1 += part2[k * 512 + c]; s2 += part2[k * 512 + 256 + c]; }
        float m = s1 * invN;
        float var = s2 * invN - m * m;
        float sc = g[c] * rsqrtf(var + EPSV);
        sss[c] = sc;
        sss[256 + c] = beta[c] - m * sc;
    }
    __syncthreads();
}

// ---------------- aggregation (plain): input already BN'd/folded ----------------
__global__ __launch_bounds__(256) void aggregate_bf16(const unsigned short* __restrict__ h,
                          const int* __restrict__ csr_src, const int* __restrict__ row_ptr,
                          const float* __restrict__ norm_dst,
                          unsigned short* __restrict__ out, int N) {
    int node = (blockIdx.x * blockDim.x + threadIdx.x) >> 6;
    int lane = threadIdx.x & 63;
    if (node >= N) return;
    int beg = row_ptr[node], end = row_ptr[node + 1];
    int half = lane >> 5;
    int cg = (lane & 31) << 3;
    float acc[8] = {};
    int e = beg;
    for (; e + 7 < end; e += 8) {
        int i0 = csr_src[e + half];
        int i1 = csr_src[e + 2 + half];
        int i2 = csr_src[e + 4 + half];
        int i3 = csr_src[e + 6 + half];
        ushort8v v0 = *(const ushort8v*)(h + (size_t)i0 * 256 + cg);
        ushort8v v1 = *(const ushort8v*)(h + (size_t)i1 * 256 + cg);
        ushort8v v2 = *(const ushort8v*)(h + (size_t)i2 * 256 + cg);
        ushort8v v3 = *(const ushort8v*)(h + (size_t)i3 * 256 + cg);
        #pragma unroll
        for (int j = 0; j < 8; ++j)
            acc[j] += (bf2f(v0[j]) + bf2f(v1[j])) + (bf2f(v2[j]) + bf2f(v3[j]));
    }
    for (; e + 1 < end; e += 2) {
        int i0 = csr_src[e + half];
        ushort8v v0 = *(const ushort8v*)(h + (size_t)i0 * 256 + cg);
        #pragma unroll
        for (int j = 0; j < 8; ++j) acc[j] += bf2f(v0[j]);
    }
    if (e < end && half == 0) {
        int i0 = csr_src[e];
        ushort8v v0 = *(const ushort8v*)(h + (size_t)i0 * 256 + cg);
        #pragma unroll
        for (int j = 0; j < 8; ++j) acc[j] += bf2f(v0[j]);
    }
    #pragma unroll
    for (int j = 0; j < 8; ++j) acc[j] += __shfl_xor(acc[j], 32, 64);
    if (half == 0) {
        float nd = norm_dst[node];
        ushort8v o;
        #pragma unroll
        for (int j = 0; j < 8; ++j) o[j] = f2bf(acc[j] * nd);
        *(ushort8v*)(out + (size_t)node * 256 + cg) = o;
    }
}

// ---------------- aggregation with fused BN derive+apply+ReLU+norm_src ----------------
__global__ __launch_bounds__(256) void aggregate_bn_fused(const unsigned short* __restrict__ y,
                          const float* __restrict__ part2, const float* __restrict__ g,
                          const float* __restrict__ beta, float invN,
                          const float* __restrict__ norm_src,
                          const int* __restrict__ csr_src, const int* __restrict__ row_ptr,
                          const float* __restrict__ norm_dst,
                          unsigned short* __restrict__ out, int N) {
    __shared__ float sss[512];
    bn_derive(part2, g, beta, invN, sss, threadIdx.x);
    int node = (blockIdx.x * blockDim.x + threadIdx.x) >> 6;
    int lane = threadIdx.x & 63;
    if (node >= N) return;
    int beg = row_ptr[node], end = row_ptr[node + 1];
    int half = lane >> 5;
    int cg = (lane & 31) << 3;
    float scv[8], shv[8];
    #pragma unroll
    for (int j = 0; j < 8; ++j) { scv[j] = sss[cg + j]; shv[j] = sss[256 + cg + j]; }
    float acc[8] = {};
    int e = beg;
    for (; e + 7 < end; e += 8) {
        int i0 = csr_src[e + half];
        int i1 = csr_src[e + 2 + half];
        int i2 = csr_src[e + 4 + half];
        int i3 = csr_src[e + 6 + half];
        float n0 = norm_src[i0], n1 = norm_src[i1], n2 = norm_src[i2], n3 = norm_src[i3];
        ushort8v v0 = *(const ushort8v*)(y + (size_t)i0 * 256 + cg);
        ushort8v v1 = *(const ushort8v*)(y + (size_t)i1 * 256 + cg);
        ushort8v v2 = *(const ushort8v*)(y + (size_t)i2 * 256 + cg);
        ushort8v v3 = *(const ushort8v*)(y + (size_t)i3 * 256 + cg);
        #pragma unroll
        for (int j = 0; j < 8; ++j) {
            acc[j] += n0 * fmaxf(0.f, bf2f(v0[j]) * scv[j] + shv[j]);
            acc[j] += n1 * fmaxf(0.f, bf2f(v1[j]) * scv[j] + shv[j]);
            acc[j] += n2 * fmaxf(0.f, bf2f(v2[j]) * scv[j] + shv[j]);
            acc[j] += n3 * fmaxf(0.f, bf2f(v3[j]) * scv[j] + shv[j]);
        }
    }
    for (; e + 1 < end; e += 2) {
        int i0 = csr_src[e + half];
        float n0 = norm_src[i0];
        ushort8v v0 = *(const ushort8v*)(y + (size_t)i0 * 256 + cg);
        #pragma unroll
        for (int j = 0; j < 8; ++j)
            acc[j] += n0 * fmaxf(0.f, bf2f(v0[j]) * scv[j] + shv[j]);
    }
    if (e < end && half == 0) {
        int i0 = csr_src[e];
        float n0 = norm_src[i0];
        ushort8v v0 = *(const ushort8v*)(y + (size_t)i0 * 256 + cg);
        #pragma unroll
        for (int j = 0; j < 8; ++j)
            acc[j] += n0 * fmaxf(0.f, bf2f(v0[j]) * scv[j] + shv[j]);
    }
    #pragma unroll
    for (int j = 0; j < 8; ++j) acc[j] += __shfl_xor(acc[j], 32, 64);
    if (half == 0) {
        float nd = norm_dst[node];
        ushort8v o;
        #pragma unroll
        for (int j = 0; j < 8; ++j) o[j] = f2bf(acc[j] * nd);
        *(ushort8v*)(out + (size_t)node * 256 + cg) = o;
    }
}

// ---------------- MFMA GEMM: 2-phase dbuf staging, LDS-relayout C-write, stats partials ----------------
__global__ __launch_bounds__(256) void gemm_mfma(const unsigned short* __restrict__ A,
                          const unsigned short* __restrict__ Bt,
                          const float* __restrict__ bias, float* __restrict__ Cf,
                          unsigned short* __restrict__ Cbf,
                          float* __restrict__ statsPart, int M, int ncols) {
    __shared__ char smem[32768];          // [A dbuf 16KB][B dbuf 16KB]; reused as 4x8KB C-tiles
    __shared__ float sstat[256];
    int tid = threadIdx.x;
    int wid = tid >> 6, lane = tid & 63;
    int wm = wid >> 1, wn = wid & 1;
    size_t row0 = (size_t)blockIdx.x * 128;
    int n0 = blockIdx.y * 128;
    f32x4 acc[4][4] = {};
    const char* Ab = (const char*)(A + row0 * 256);
    const char* Bb = (const char*)(Bt + (size_t)n0 * 256);
    char* AsB = smem;
    char* BsB = smem + 16384;
    if (tid < 256) sstat[tid] = 0.f;

    auto STAGE = [&](int buf, int k0) {
        #pragma unroll
        for (int j = 0; j < 2; ++j) {
            int boff = (wid * 2 + j) * 1024 + lane * 16;
            int row = boff >> 6, col = boff & 63;
            gload_lds16(Ab + (size_t)row * 512 + (size_t)k0 * 2 + col, AsB + buf * 8192 + (wid * 2 + j) * 1024);
            gload_lds16(Bb + (size_t)row * 512 + (size_t)k0 * 2 + col, BsB + buf * 8192 + (wid * 2 + j) * 1024);
        }
    };

    STAGE(0, 0);
    __syncthreads();
    for (int t = 0; t < 8; ++t) {
        int cur = t & 1;
        if (t < 7) STAGE(cur ^ 1, (t + 1) * 32);
        const char* Ac = AsB + cur * 8192;
        const char* Bc = BsB + cur * 8192;
        bfv8 af[4], bfr[4];
        #pragma unroll
        for (int m = 0; m < 4; ++m)
            af[m] = *(const bfv8*)(Ac + ((wm * 64 + m * 16 + (lane & 15)) * 64 + (lane >> 4) * 16));
        #pragma unroll
        for (int n = 0; n < 4; ++n)
            bfr[n] = *(const bfv8*)(Bc + ((wn * 64 + n * 16 + (lane & 15)) * 64 + (lane >> 4) * 16));
        #pragma unroll
        for (int m = 0; m < 4; ++m)
            #pragma unroll
            for (int n = 0; n < 4; ++n)
                acc[m][n] = __builtin_amdgcn_mfma_f32_16x16x32_bf16(af[m], bfr[n], acc[m][n], 0, 0, 0);
        __syncthreads();
    }

    if (statsPart) {
        #pragma unroll
        for (int n = 0; n < 4; ++n) {
            float s1 = 0.f, s2 = 0.f;
            #pragma unroll
            for (int m = 0; m < 4; ++m) {
                size_t rbase = row0 + wm * 64 + m * 16 + ((lane >> 4) << 2);
                #pragma unroll
                for (int r = 0; r < 4; ++r) {
                    float v = ((rbase + r) < (size_t)M) ? acc[m][n][r] : 0.f;
                    s1 += v;
                    s2 += v * v;
                }
            }
            s1 += __shfl_xor(s1, 16, 64); s1 += __shfl_xor(s1, 32, 64);
            s2 += __shfl_xor(s2, 16, 64); s2 += __shfl_xor(s2, 32, 64);
            if (lane < 16) {
                int lc = wn * 64 + n * 16 + lane;
                atomicAdd(&sstat[lc], s1);
                atomicAdd(&sstat[128 + lc], s2);
            }
        }
        __syncthreads();
        if (tid < 256)
            statsPart[((size_t)blockIdx.x * gridDim.y + blockIdx.y) * 256 + tid] = sstat[tid];
    }

    if (Cbf) {
        char* creg = smem + wid * 8192;
        #pragma unroll
        for (int m = 0; m < 4; ++m)
            #pragma unroll
            for (int n = 0; n < 4; ++n) {
                int col = n * 16 + (lane & 15);
                #pragma unroll
                for (int r = 0; r < 4; ++r) {
                    int row = m * 16 + ((lane >> 4) << 2) + r;
                    *(unsigned short*)(creg + row * 128 + col * 2) = f2bf(acc[m][n][r]);
                }
            }
        #pragma unroll
        for (int p = 0; p < 8; ++p) {
            int row = p * 8 + (lane >> 3);
            int slot = lane & 7;
            size_t grow = row0 + wm * 64 + row;
            if (grow < (size_t)M)
                *(ushort8v*)(Cbf + grow * ncols + n0 + wn * 64 + slot * 8) =
                    *(const ushort8v*)(creg + row * 128 + slot * 16);
        }
    } else {
        #pragma unroll
        for (int n = 0; n < 4; ++n) {
            int col = n0 + wn * 64 + n * 16 + (lane & 15);
            if (col < ncols) {
                float b = bias ? bias[col] : 0.0f;
                #pragma unroll
                for (int m = 0; m < 4; ++m) {
                    size_t rbase = row0 + wm * 64 + m * 16 + ((lane >> 4) << 2);
                    #pragma unroll
                    for (int r = 0; r < 4; ++r) {
                        size_t row = rbase + r;
                        if (row < (size_t)M)
                            Cf[row * ncols + col] = acc[m][n][r] + b;
                    }
                }
            }
        }
    }
}

// ---------------- BN stats reduction (8 blocks; final derive folded into consumers) ----------------
__global__ void bn_reduce(const float* __restrict__ part, float* __restrict__ part2, int nbx, int chunk) {
    int g = blockIdx.x, t = threadIdx.x;     // grid(8), 512 threads
    int b0 = g * chunk, b1 = min(b0 + chunk, nbx);
    int by, elem;
    if (t < 256) { by = t >> 7; elem = t & 127; }
    else { int c = t - 256; by = c >> 7; elem = 128 + (c & 127); }
    float s = 0.f;
    for (int bx = b0; bx < b1; ++bx)
        s += part[((size_t)bx * 2 + by) * 256 + elem];
    part2[g * 512 + t] = s;
}

// ---------------- BN apply (bf16 in, bf16 out) — last layer only; derives ss itself ----------------
__global__ __launch_bounds__(256) void bn_relu_cvt(const unsigned short* __restrict__ y,
                            const float* __restrict__ part2, const float* __restrict__ g,
                            const float* __restrict__ beta, float invN,
                            unsigned short* __restrict__ out, int N) {
    __shared__ float sss[512];
    bn_derive(part2, g, beta, invN, sss, threadIdx.x);
    int i = blockIdx.x * blockDim.x + threadIdx.x;
    if (i >= N * 64) return;
    int node = i >> 6;
    int c4 = (i & 63) << 2;
    float4 sc = *(const float4*)(sss + c4);
    float4 sh = *(const float4*)(sss + 256 + c4);
    ushort4 yv = *(const ushort4*)(y + (size_t)node * 256 + c4);
    ushort4 o;
    o.x = f2bf(fmaxf(0.f, bf2f(yv.x) * sc.x + sh.x));
    o.y = f2bf(fmaxf(0.f, bf2f(yv.y) * sc.y + sh.y));
    o.z = f2bf(fmaxf(0.f, bf2f(yv.z) * sc.z + sh.z));
    o.w = f2bf(fmaxf(0.f, bf2f(yv.w) * sc.w + sh.w));
    *(ushort4*)(out + (size_t)node * 256 + c4) = o;
}

// ---------------- launch ----------------
extern "C" void kernel_launch(void* const* d_in, const int* in_sizes, int n_in,
                              void* d_out, int out_size, void* d_ws, size_t ws_size,
                              hipStream_t stream) {
    const float* x   = (const float*)d_in[0];
    const int* src   = (const int*)d_in[1];
    const int* dst   = (const int*)d_in[2];
    const float* Ws_[3]    = {(const float*)d_in[3], (const float*)d_in[7],  (const float*)d_in[11]};
    const float* gs_[3]    = {(const float*)d_in[5], (const float*)d_in[9],  (const float*)d_in[13]};
    const float* betas_[3] = {(const float*)d_in[6], (const float*)d_in[10], (const float*)d_in[14]};
    const float* fcW = (const float*)d_in[15];
    const float* fcb = (const float*)d_in[16];
    float* out = (float*)d_out;

    const int N = in_sizes[0] / C_IN;
    const int E = in_sizes[1];
    const int Npad = ((N + 127) / 128) * 128;
    const int nScanBlocks = (N + 1023) / 1024;
    const int epc = (E + ECHUNK - 1) / ECHUNK;
    const int bpc = ((epc + 3) / 4 + 255) / 256;
    const int gemm_rows = Npad / 128;
    const int chunk = (gemm_rows + 7) / 8;

    char* ws = (char*)d_ws;
    size_t o = 0;
    auto alloc = [&](size_t bytes) { size_t p = o; o = (o + bytes + 511) & ~(size_t)511; return p; };
    float* norm_src = (float*)(ws + alloc((size_t)N * 4));
    int* cnt_in     = (int*)(ws + alloc((size_t)N * 4));
    float* norm_dst = (float*)(ws + alloc((size_t)N * 4));
    int* row_ptr    = (int*)(ws + alloc((size_t)(N + 1) * 4));
    int* block_sums = (int*)(ws + alloc((size_t)(nScanBlocks + 1) * 4));
    int* csr_src    = (int*)(ws + alloc((size_t)E * 4));
    unsigned short* rank = (unsigned short*)(ws + alloc((size_t)E * 2));
    unsigned int* partpk = (unsigned int*)(ws + alloc((size_t)ECHUNK * NPAD2 * 4));
    unsigned short* chunk_off = (unsigned short*)(ws + alloc((size_t)ECHUNK * NPAD2 * 2));
    float* statsPart= (float*)(ws + alloc((size_t)gemm_rows * 2 * 256 * 4));
    float* part2    = (float*)(ws + alloc(8 * 512 * 4));
    unsigned short* Wt[3];
    Wt[0] = (unsigned short*)(ws + alloc(256 * 256 * 2));
    Wt[1] = (unsigned short*)(ws + alloc(256 * 256 * 2));
    Wt[2] = (unsigned short*)(ws + alloc(256 * 256 * 2));
    unsigned short* Wtfc = (unsigned short*)(ws + alloc(128 * 256 * 2));
    unsigned short* hbuf   = (unsigned short*)(ws + alloc((size_t)Npad * 256 * 2));
    unsigned short* aggbuf = (unsigned short*)(ws + alloc((size_t)Npad * 256 * 2));
    unsigned short* ybuf   = (unsigned short*)(ws + alloc((size_t)Npad * 256 * 2));
    (void)ws_size; (void)n_in; (void)out_size;

    // graph prep: no global atomics anywhere
    hist_pass<<<NCHUNK * ECHUNK, 256, 0, stream>>>(src, dst, partpk, rank, E, epc);
    reduce_scan<<<(N + 255) / 256, 256, 0, stream>>>(partpk, chunk_off, norm_src, cnt_in, N);
    scan_blocks<<<nScanBlocks, 256, 0, stream>>>(cnt_in, norm_src, norm_dst, row_ptr, block_sums, N);
    scan_add<<<(N + 255) / 256, 256, 0, stream>>>(row_ptr, block_sums, N, E, nScanBlocks);
    csr_scatter<<<ECHUNK * bpc, 256, 0, stream>>>(src, dst, rank, row_ptr, chunk_off, csr_src, E, epc, bpc);

    cvt_w_all<<<(3 * 65536 + 128 * 256 + 255) / 256, 256, 0, stream>>>(
        Ws_[0], Ws_[1], Ws_[2], fcW, Wt[0], Wt[1], Wt[2], Wtfc);

    int nb64 = (N * 64 + 255) / 256;
    cvt_x<<<nb64, 256, 0, stream>>>(x, norm_src, hbuf, N);

    int agg_blocks = (N + 3) / 4;
    float invN = 1.0f / (float)N;

    for (int layer = 0; layer < 3; ++layer) {
        if (layer == 0)
            aggregate_bf16<<<agg_blocks, 256, 0, stream>>>(hbuf, csr_src, row_ptr, norm_dst, aggbuf, N);
        else
            aggregate_bn_fused<<<agg_blocks, 256, 0, stream>>>(ybuf, part2, gs_[layer - 1], betas_[layer - 1],
                                                               invN, norm_src, csr_src, row_ptr,
                                                               norm_dst, aggbuf, N);
        gemm_mfma<<<dim3(gemm_rows, 2), 256, 0, stream>>>(aggbuf, Wt[layer], nullptr, nullptr, ybuf,
                                                          statsPart, N, C_HID);
        bn_reduce<<<8, 512, 0, stream>>>(statsPart, part2, gemm_rows, chunk);
    }
    // last layer BN applied standalone (no next aggregate to fuse into)
    bn_relu_cvt<<<nb64, 256, 0, stream>>>(ybuf, part2, gs_[2], betas_[2], invN, hbuf, N);
    gemm_mfma<<<dim3(gemm_rows, 1), 256, 0, stream>>>(hbuf, Wtfc, fcb, out, nullptr, nullptr, N, C_OUT);
}

// Round 15
// 379.989 us; speedup vs baseline: 1.6875x; 1.0110x over previous
//
#include <hip/hip_runtime.h>
#include <hip/hip_bf16.h>

#define C_IN 256
#define C_HID 256
#define C_OUT 64
#define EPSV 1e-5f

// graph-prep histogram geometry
#define NCHUNK 8
#define NCHUNK_LOG 3
#define RANGE 6272           // 8*6272 = 50176 >= N
#define NPAD2 (NCHUNK * RANGE)
#define ECHUNK 64

typedef __bf16 bfv8 __attribute__((ext_vector_type(8)));
typedef float f32x4 __attribute__((ext_vector_type(4)));
typedef unsigned short ushort8v __attribute__((ext_vector_type(8)));

__device__ __forceinline__ float bf2f(unsigned short u) {
    return __uint_as_float(((unsigned int)u) << 16);
}
__device__ __forceinline__ unsigned short f2bf(float f) {
    unsigned int u = __float_as_uint(f);
    unsigned int r = (u + 0x7fffu + ((u >> 16) & 1u)) >> 16;
    return (unsigned short)r;
}

__device__ __forceinline__ void gload_lds16(const void* g, void* l) {
    __builtin_amdgcn_global_load_lds(
        (const __attribute__((address_space(1))) unsigned int*)g,
        (__attribute__((address_space(3))) unsigned int*)l, 16, 0, 0);
}

// ---------------- pass 1: packed LDS histograms (src=low16, dst=high16) + per-edge rank ----------------
__global__ __launch_bounds__(256) void hist_pass(const int* __restrict__ src, const int* __restrict__ dst,
        unsigned int* __restrict__ partpk, unsigned short* __restrict__ rank,
        int E, int epc) {
    __shared__ unsigned int hist[RANGE];   // low16: src count, high16: dst count
    int nc = blockIdx.x & (NCHUNK - 1);
    int ec = blockIdx.x >> NCHUNK_LOG;
    int vbase = nc * RANGE;
    for (int i = threadIdx.x; i < RANGE; i += 256) hist[i] = 0;
    __syncthreads();
    int e0 = ec * epc, e1 = min(e0 + epc, E);
    for (int e = e0 + threadIdx.x * 4; e < e1; e += 1024) {
        if (e + 3 < e1) {
            int4 s4 = *(const int4*)(src + e);
            int4 d4 = *(const int4*)(dst + e);
            int sv[4] = {s4.x, s4.y, s4.z, s4.w};
            int dv[4] = {d4.x, d4.y, d4.z, d4.w};
            #pragma unroll
            for (int j = 0; j < 4; ++j) {
                unsigned rs = (unsigned)(sv[j] - vbase);
                unsigned rd = (unsigned)(dv[j] - vbase);
                if (rs < RANGE) atomicAdd(&hist[rs], 1u);
                if (rd < RANGE) {
                    unsigned old = atomicAdd(&hist[rd], 0x10000u);
                    rank[e + j] = (unsigned short)(old >> 16);
                }
            }
        } else {
            for (int j = 0; j < 4 && e + j < e1; ++j) {
                unsigned rs = (unsigned)(src[e + j] - vbase);
                unsigned rd = (unsigned)(dst[e + j] - vbase);
                if (rs < RANGE) atomicAdd(&hist[rs], 1u);
                if (rd < RANGE) {
                    unsigned old = atomicAdd(&hist[rd], 0x10000u);
                    rank[e + j] = (unsigned short)(old >> 16);
                }
            }
        }
    }
    __syncthreads();
    size_t base = (size_t)ec * NPAD2 + vbase;
    for (int i = threadIdx.x; i < RANGE; i += 256)
        partpk[base + i] = hist[i];
}

// ---------------- reduce partials: deg_out, cnt_in, per-chunk exclusive offsets (u16) ----------------
__global__ void reduce_scan(const unsigned int* __restrict__ partpk, unsigned short* __restrict__ chunk_off,
                            float* __restrict__ deg_out, int* __restrict__ cnt_in, int N) {
    int v = blockIdx.x * 256 + threadIdx.x;
    if (v >= N) return;
    int ssum = 0, run = 0;
    #pragma unroll 8
    for (int ec = 0; ec < ECHUNK; ++ec) {
        unsigned p = partpk[(size_t)ec * NPAD2 + v];
        ssum += (int)(p & 0xFFFFu);
        chunk_off[(size_t)ec * NPAD2 + v] = (unsigned short)run;
        run += (int)(p >> 16);
    }
    deg_out[v] = (float)ssum;
    cnt_in[v] = run;
}

// ---------------- scan phase 1 + norms ----------------
__global__ __launch_bounds__(256) void scan_blocks(const int* __restrict__ cnt_in,
        float* __restrict__ deg_out_to_norm_src, float* __restrict__ norm_dst,
        int* __restrict__ row_ptr, int* __restrict__ block_sums, int N) {
    __shared__ int wave_sums[4];
    int b = blockIdx.x;
    int tid = threadIdx.x;
    int lane = tid & 63, w = tid >> 6;
    int idx = b * 1024 + tid * 4;
    int4 v = {0, 0, 0, 0};
    if (idx + 3 < N) v = *(const int4*)(cnt_in + idx);
    else {
        if (idx + 0 < N) v.x = cnt_in[idx + 0];
        if (idx + 1 < N) v.y = cnt_in[idx + 1];
        if (idx + 2 < N) v.z = cnt_in[idx + 2];
        if (idx + 3 < N) v.w = cnt_in[idx + 3];
    }
    int tsum = v.x + v.y + v.z + v.w;
    int s = tsum;
    #pragma unroll
    for (int off = 1; off < 64; off <<= 1) {
        int t = __shfl_up(s, off, 64);
        if (lane >= off) s += t;
    }
    if (lane == 63) wave_sums[w] = s;
    __syncthreads();
    int woff = 0;
    for (int i = 0; i < w; ++i) woff += wave_sums[i];
    int excl = woff + s - tsum;
    int p0 = excl, p1 = p0 + v.x, p2 = p1 + v.y, p3 = p2 + v.z;
    if (idx + 3 < N) {
        *(int4*)(row_ptr + idx) = make_int4(p0, p1, p2, p3);
        float4 d = *(const float4*)(deg_out_to_norm_src + idx);
        float4 ns, nd;
        ns.x = d.x > 0.f ? rsqrtf(d.x) : 0.f;
        ns.y = d.y > 0.f ? rsqrtf(d.y) : 0.f;
        ns.z = d.z > 0.f ? rsqrtf(d.z) : 0.f;
        ns.w = d.w > 0.f ? rsqrtf(d.w) : 0.f;
        nd.x = v.x > 0 ? rsqrtf((float)v.x) : 0.f;
        nd.y = v.y > 0 ? rsqrtf((float)v.y) : 0.f;
        nd.z = v.z > 0 ? rsqrtf((float)v.z) : 0.f;
        nd.w = v.w > 0 ? rsqrtf((float)v.w) : 0.f;
        *(float4*)(deg_out_to_norm_src + idx) = ns;
        *(float4*)(norm_dst + idx) = nd;
    } else {
        int ps[4] = {p0, p1, p2, p3};
        int cs[4] = {v.x, v.y, v.z, v.w};
        for (int j = 0; j < 4; ++j) {
            int i2 = idx + j;
            if (i2 < N) {
                row_ptr[i2] = ps[j];
                float d = deg_out_to_norm_src[i2];
                deg_out_to_norm_src[i2] = d > 0.f ? rsqrtf(d) : 0.f;
                norm_dst[i2] = cs[j] > 0 ? rsqrtf((float)cs[j]) : 0.f;
            }
        }
    }
    if (tid == 255) block_sums[b] = woff + s;
}

// ---------------- scan phase 2+3 merged ----------------
__global__ void scan_add(int* __restrict__ row_ptr, const int* __restrict__ bs, int N, int E, int nb) {
    __shared__ int soff[256];
    int tid = threadIdx.x;
    if (tid < 64) {
        int carry = 0;
        for (int base = 0; base < nb; base += 64) {
            int i = base + tid;
            int v = (i < nb) ? bs[i] : 0;
            int s = v;
            #pragma unroll
            for (int off = 1; off < 64; off <<= 1) {
                int t = __shfl_up(s, off, 64);
                if (tid >= off) s += t;
            }
            if (i < nb && i < 256) soff[i] = carry + s - v;
            carry += __shfl(s, 63, 64);
        }
    }
    __syncthreads();
    int i = blockIdx.x * blockDim.x + tid;
    if (i == 0) row_ptr[N] = E;
    if (i < N) row_ptr[i] += soff[i >> 10];
}

// ---------------- pass 2: flat CSR scatter, int4-vectorized ----------------
__global__ __launch_bounds__(256) void csr_scatter(const int* __restrict__ src, const int* __restrict__ dst,
        const unsigned short* __restrict__ rank, const int* __restrict__ row_ptr,
        const unsigned short* __restrict__ chunk_off, int* __restrict__ csr_src, int E, int epc, int bpc) {
    int ec = blockIdx.x / bpc;
    int off4 = ((blockIdx.x - ec * bpc) * 256 + threadIdx.x) * 4;
    if (off4 >= epc) return;
    int e = ec * epc + off4;
    int e1 = min(ec * epc + epc, E);
    if (e >= e1) return;
    const unsigned short* coff = chunk_off + (size_t)ec * NPAD2;
    if (e + 3 < e1) {
        int4 s4 = *(const int4*)(src + e);
        int4 d4 = *(const int4*)(dst + e);
        ushort4 r4 = *(const ushort4*)(rank + e);
        int dv[4] = {d4.x, d4.y, d4.z, d4.w};
        int sv[4] = {s4.x, s4.y, s4.z, s4.w};
        int rv[4] = {r4.x, r4.y, r4.z, r4.w};
        #pragma unroll
        for (int j = 0; j < 4; ++j) {
            int d = dv[j];
            csr_src[row_ptr[d] + (int)coff[d] + rv[j]] = sv[j];
        }
    } else {
        for (int j = 0; j < 4 && e + j < e1; ++j) {
            int d = dst[e + j];
            csr_src[row_ptr[d] + (int)coff[d] + (int)rank[e + j]] = src[e + j];
        }
    }
}

// ---------------- conversions ----------------
__global__ void cvt_x(const float* __restrict__ x, const float* __restrict__ norm_src,
                      unsigned short* __restrict__ hs, int N) {
    int i = blockIdx.x * blockDim.x + threadIdx.x;
    if (i >= N * 64) return;
    int node = i >> 6;
    int c4 = (i & 63) << 2;
    float4 v = *(const float4*)(x + (size_t)node * 256 + c4);
    float f = norm_src[node];
    ushort4 o;
    o.x = f2bf(v.x * f); o.y = f2bf(v.y * f); o.z = f2bf(v.z * f); o.w = f2bf(v.w * f);
    *(ushort4*)(hs + (size_t)node * 256 + c4) = o;
}

__global__ void cvt_w_all(const float* __restrict__ W0, const float* __restrict__ W1,
                          const float* __restrict__ W2, const float* __restrict__ Wfc,
                          unsigned short* __restrict__ T0, unsigned short* __restrict__ T1,
                          unsigned short* __restrict__ T2, unsigned short* __restrict__ Tfc) {
    int idx = blockIdx.x * 256 + threadIdx.x;
    if (idx < 3 * 65536) {
        int l = idx >> 16, r = idx & 65535;
        const float* W = (l == 0) ? W0 : (l == 1) ? W1 : W2;
        unsigned short* T = (l == 0) ? T0 : (l == 1) ? T1 : T2;
        int n = r >> 8, k = r & 255;
        T[r] = f2bf(W[(size_t)k * 256 + n]);
    } else {
        int r = idx - 3 * 65536;
        if (r < 128 * 256) {
            int n = r >> 8, k = r & 255;
            Tfc[r] = f2bf((n < 64) ? Wfc[(size_t)k * 64 + n] : 0.f);
        }
    }
}

// ---------------- aggregation (plain): input already BN'd/folded ----------------
__global__ __launch_bounds__(256) void aggregate_bf16(const unsigned short* __restrict__ h,
                          const int* __restrict__ csr_src, const int* __restrict__ row_ptr,
                          const float* __restrict__ norm_dst,
                          unsigned short* __restrict__ out, int N) {
    int node = (blockIdx.x * blockDim.x + threadIdx.x) >> 6;
    int lane = threadIdx.x & 63;
    if (node >= N) return;
    int beg = row_ptr[node], end = row_ptr[node + 1];
    int half = lane >> 5;
    int cg = (lane & 31) << 3;
    float acc[8] = {};
    int e = beg;
    for (; e + 7 < end; e += 8) {
        int i0 = csr_src[e + half];
        int i1 = csr_src[e + 2 + half];
        int i2 = csr_src[e + 4 + half];
        int i3 = csr_src[e + 6 + half];
        ushort8v v0 = *(const ushort8v*)(h + (size_t)i0 * 256 + cg);
        ushort8v v1 = *(const ushort8v*)(h + (size_t)i1 * 256 + cg);
        ushort8v v2 = *(const ushort8v*)(h + (size_t)i2 * 256 + cg);
        ushort8v v3 = *(const ushort8v*)(h + (size_t)i3 * 256 + cg);
        #pragma unroll
        for (int j = 0; j < 8; ++j)
            acc[j] += (bf2f(v0[j]) + bf2f(v1[j])) + (bf2f(v2[j]) + bf2f(v3[j]));
    }
    for (; e + 1 < end; e += 2) {
        int i0 = csr_src[e + half];
        ushort8v v0 = *(const ushort8v*)(h + (size_t)i0 * 256 + cg);
        #pragma unroll
        for (int j = 0; j < 8; ++j) acc[j] += bf2f(v0[j]);
    }
    if (e < end && half == 0) {
        int i0 = csr_src[e];
        ushort8v v0 = *(const ushort8v*)(h + (size_t)i0 * 256 + cg);
        #pragma unroll
        for (int j = 0; j < 8; ++j) acc[j] += bf2f(v0[j]);
    }
    #pragma unroll
    for (int j = 0; j < 8; ++j) acc[j] += __shfl_xor(acc[j], 32, 64);
    if (half == 0) {
        float nd = norm_dst[node];
        ushort8v o;
        #pragma unroll
        for (int j = 0; j < 8; ++j) o[j] = f2bf(acc[j] * nd);
        *(ushort8v*)(out + (size_t)node * 256 + cg) = o;
    }
}

// ---------------- aggregation with fused BN apply+ReLU+norm_src (ss precomputed) ----------------
__global__ __launch_bounds__(256) void aggregate_bn_fused(const unsigned short* __restrict__ y,
                          const float* __restrict__ ss, const float* __restrict__ norm_src,
                          const int* __restrict__ csr_src, const int* __restrict__ row_ptr,
                          const float* __restrict__ norm_dst,
                          unsigned short* __restrict__ out, int N) {
    int node = (blockIdx.x * blockDim.x + threadIdx.x) >> 6;
    int lane = threadIdx.x & 63;
    if (node >= N) return;
    int beg = row_ptr[node], end = row_ptr[node + 1];
    int half = lane >> 5;
    int cg = (lane & 31) << 3;
    float scv[8], shv[8];
    {
        float4 a = *(const float4*)(ss + cg);
        float4 b = *(const float4*)(ss + cg + 4);
        float4 c = *(const float4*)(ss + 256 + cg);
        float4 d = *(const float4*)(ss + 256 + cg + 4);
        scv[0]=a.x; scv[1]=a.y; scv[2]=a.z; scv[3]=a.w; scv[4]=b.x; scv[5]=b.y; scv[6]=b.z; scv[7]=b.w;
        shv[0]=c.x; shv[1]=c.y; shv[2]=c.z; shv[3]=c.w; shv[4]=d.x; shv[5]=d.y; shv[6]=d.z; shv[7]=d.w;
    }
    float acc[8] = {};
    int e = beg;
    for (; e + 7 < end; e += 8) {
        int i0 = csr_src[e + half];
        int i1 = csr_src[e + 2 + half];
        int i2 = csr_src[e + 4 + half];
        int i3 = csr_src[e + 6 + half];
        float n0 = norm_src[i0], n1 = norm_src[i1], n2 = norm_src[i2], n3 = norm_src[i3];
        ushort8v v0 = *(const ushort8v*)(y + (size_t)i0 * 256 + cg);
        ushort8v v1 = *(const ushort8v*)(y + (size_t)i1 * 256 + cg);
        ushort8v v2 = *(const ushort8v*)(y + (size_t)i2 * 256 + cg);
        ushort8v v3 = *(const ushort8v*)(y + (size_t)i3 * 256 + cg);
        #pragma unroll
        for (int j = 0; j < 8; ++j) {
            acc[j] += n0 * fmaxf(0.f, bf2f(v0[j]) * scv[j] + shv[j]);
            acc[j] += n1 * fmaxf(0.f, bf2f(v1[j]) * scv[j] + shv[j]);
            acc[j] += n2 * fmaxf(0.f, bf2f(v2[j]) * scv[j] + shv[j]);
            acc[j] += n3 * fmaxf(0.f, bf2f(v3[j]) * scv[j] + shv[j]);
        }
    }
    for (; e + 1 < end; e += 2) {
        int i0 = csr_src[e + half];
        float n0 = norm_src[i0];
        ushort8v v0 = *(const ushort8v*)(y + (size_t)i0 * 256 + cg);
        #pragma unroll
        for (int j = 0; j < 8; ++j)
            acc[j] += n0 * fmaxf(0.f, bf2f(v0[j]) * scv[j] + shv[j]);
    }
    if (e < end && half == 0) {
        int i0 = csr_src[e];
        float n0 = norm_src[i0];
        ushort8v v0 = *(const ushort8v*)(y + (size_t)i0 * 256 + cg);
        #pragma unroll
        for (int j = 0; j < 8; ++j)
            acc[j] += n0 * fmaxf(0.f, bf2f(v0[j]) * scv[j] + shv[j]);
    }
    #pragma unroll
    for (int j = 0; j < 8; ++j) acc[j] += __shfl_xor(acc[j], 32, 64);
    if (half == 0) {
        float nd = norm_dst[node];
        ushort8v o;
        #pragma unroll
        for (int j = 0; j < 8; ++j) o[j] = f2bf(acc[j] * nd);
        *(ushort8v*)(out + (size_t)node * 256 + cg) = o;
    }
}

// ---------------- MFMA GEMM: 2-phase dbuf staging, LDS-relayout C-write, stats partials ----------------
__global__ __launch_bounds__(256) void gemm_mfma(const unsigned short* __restrict__ A,
                          const unsigned short* __restrict__ Bt,
                          const float* __restrict__ bias, float* __restrict__ Cf,
                          unsigned short* __restrict__ Cbf,
                          float* __restrict__ statsPart, int M, int ncols) {
    __shared__ char smem[32768];          // [A dbuf 16KB][B dbuf 16KB]; reused as 4x8KB C-tiles
    __shared__ float sstat[256];
    int tid = threadIdx.x;
    int wid = tid >> 6, lane = tid & 63;
    int wm = wid >> 1, wn = wid & 1;
    size_t row0 = (size_t)blockIdx.x * 128;
    int n0 = blockIdx.y * 128;
    f32x4 acc[4][4] = {};
    const char* Ab = (const char*)(A + row0 * 256);
    const char* Bb = (const char*)(Bt + (size_t)n0 * 256);
    char* AsB = smem;
    char* BsB = smem + 16384;
    if (tid < 256) sstat[tid] = 0.f;

    auto STAGE = [&](int buf, int k0) {
        #pragma unroll
        for (int j = 0; j < 2; ++j) {
            int boff = (wid * 2 + j) * 1024 + lane * 16;
            int row = boff >> 6, col = boff & 63;
            gload_lds16(Ab + (size_t)row * 512 + (size_t)k0 * 2 + col, AsB + buf * 8192 + (wid * 2 + j) * 1024);
            gload_lds16(Bb + (size_t)row * 512 + (size_t)k0 * 2 + col, BsB + buf * 8192 + (wid * 2 + j) * 1024);
        }
    };

    STAGE(0, 0);
    __syncthreads();
    for (int t = 0; t < 8; ++t) {
        int cur = t & 1;
        if (t < 7) STAGE(cur ^ 1, (t + 1) * 32);
        const char* Ac = AsB + cur * 8192;
        const char* Bc = BsB + cur * 8192;
        bfv8 af[4], bfr[4];
        #pragma unroll
        for (int m = 0; m < 4; ++m)
            af[m] = *(const bfv8*)(Ac + ((wm * 64 + m * 16 + (lane & 15)) * 64 + (lane >> 4) * 16));
        #pragma unroll
        for (int n = 0; n < 4; ++n)
            bfr[n] = *(const bfv8*)(Bc + ((wn * 64 + n * 16 + (lane & 15)) * 64 + (lane >> 4) * 16));
        #pragma unroll
        for (int m = 0; m < 4; ++m)
            #pragma unroll
            for (int n = 0; n < 4; ++n)
                acc[m][n] = __builtin_amdgcn_mfma_f32_16x16x32_bf16(af[m], bfr[n], acc[m][n], 0, 0, 0);
        __syncthreads();
    }

    if (statsPart) {
        #pragma unroll
        for (int n = 0; n < 4; ++n) {
            float s1 = 0.f, s2 = 0.f;
            #pragma unroll
            for (int m = 0; m < 4; ++m) {
                size_t rbase = row0 + wm * 64 + m * 16 + ((lane >> 4) << 2);
                #pragma unroll
                for (int r = 0; r < 4; ++r) {
                    float v = ((rbase + r) < (size_t)M) ? acc[m][n][r] : 0.f;
                    s1 += v;
                    s2 += v * v;
                }
            }
            s1 += __shfl_xor(s1, 16, 64); s1 += __shfl_xor(s1, 32, 64);
            s2 += __shfl_xor(s2, 16, 64); s2 += __shfl_xor(s2, 32, 64);
            if (lane < 16) {
                int lc = wn * 64 + n * 16 + lane;
                atomicAdd(&sstat[lc], s1);
                atomicAdd(&sstat[128 + lc], s2);
            }
        }
        __syncthreads();
        if (tid < 256)
            statsPart[((size_t)blockIdx.x * gridDim.y + blockIdx.y) * 256 + tid] = sstat[tid];
    }

    if (Cbf) {
        char* creg = smem + wid * 8192;
        #pragma unroll
        for (int m = 0; m < 4; ++m)
            #pragma unroll
            for (int n = 0; n < 4; ++n) {
                int col = n * 16 + (lane & 15);
                #pragma unroll
                for (int r = 0; r < 4; ++r) {
                    int row = m * 16 + ((lane >> 4) << 2) + r;
                    *(unsigned short*)(creg + row * 128 + col * 2) = f2bf(acc[m][n][r]);
                }
            }
        #pragma unroll
        for (int p = 0; p < 8; ++p) {
            int row = p * 8 + (lane >> 3);
            int slot = lane & 7;
            size_t grow = row0 + wm * 64 + row;
            if (grow < (size_t)M)
                *(ushort8v*)(Cbf + grow * ncols + n0 + wn * 64 + slot * 8) =
                    *(const ushort8v*)(creg + row * 128 + slot * 16);
        }
    } else {
        #pragma unroll
        for (int n = 0; n < 4; ++n) {
            int col = n0 + wn * 64 + n * 16 + (lane & 15);
            if (col < ncols) {
                float b = bias ? bias[col] : 0.0f;
                #pragma unroll
                for (int m = 0; m < 4; ++m) {
                    size_t rbase = row0 + wm * 64 + m * 16 + ((lane >> 4) << 2);
                    #pragma unroll
                    for (int r = 0; r < 4; ++r) {
                        size_t row = rbase + r;
                        if (row < (size_t)M)
                            Cf[row * ncols + col] = acc[m][n][r] + b;
                    }
                }
            }
        }
    }
}

// ---------------- BN stats reduction (two-stage: 8 blocks then 1 tiny derive) ----------------
__global__ void bn_reduce(const float* __restrict__ part, float* __restrict__ part2, int nbx, int chunk) {
    int g = blockIdx.x, t = threadIdx.x;     // grid(8), 512 threads
    int b0 = g * chunk, b1 = min(b0 + chunk, nbx);
    int by, elem;
    if (t < 256) { by = t >> 7; elem = t & 127; }
    else { int c = t - 256; by = c >> 7; elem = 128 + (c & 127); }
    float s = 0.f;
    for (int bx = b0; bx < b1; ++bx)
        s += part[((size_t)bx * 2 + by) * 256 + elem];
    part2[g * 512 + t] = s;
}

__global__ void bn_params(const float* __restrict__ part2, const float* __restrict__ g,
                          const float* __restrict__ beta, float* __restrict__ ss, float invN) {
    int c = threadIdx.x;   // 256
    float s1 = 0.f, s2 = 0.f;
    #pragma unroll
    for (int k = 0; k < 8; ++k) { s1 += part2[k * 512 + c]; s2 += part2[k * 512 + 256 + c]; }
    float m = s1 * invN;
    float var = s2 * invN - m * m;
    float sc = g[c] * rsqrtf(var + EPSV);
    ss[c] = sc;
    ss[256 + c] = beta[c] - m * sc;
}

// ---------------- BN apply (bf16 in, bf16 out) — last layer only ----------------
__global__ void bn_relu_cvt(const unsigned short* __restrict__ y, const float* __restrict__ ss,
                            unsigned short* __restrict__ out, int N) {
    int i = blockIdx.x * blockDim.x + threadIdx.x;
    if (i >= N * 64) return;
    int node = i >> 6;
    int c4 = (i & 63) << 2;
    float4 sc = *(const float4*)(ss + c4);
    float4 sh = *(const float4*)(ss + 256 + c4);
    ushort4 yv = *(const ushort4*)(y + (size_t)node * 256 + c4);
    ushort4 o;
    o.x = f2bf(fmaxf(0.f, bf2f(yv.x) * sc.x + sh.x));
    o.y = f2bf(fmaxf(0.f, bf2f(yv.y) * sc.y + sh.y));
    o.z = f2bf(fmaxf(0.f, bf2f(yv.z) * sc.z + sh.z));
    o.w = f2bf(fmaxf(0.f, bf2f(yv.w) * sc.w + sh.w));
    *(ushort4*)(out + (size_t)node * 256 + c4) = o;
}

// ---------------- launch ----------------
extern "C" void kernel_launch(void* const* d_in, const int* in_sizes, int n_in,
                              void* d_out, int out_size, void* d_ws, size_t ws_size,
                              hipStream_t stream) {
    const float* x   = (const float*)d_in[0];
    const int* src   = (const int*)d_in[1];
    const int* dst   = (const int*)d_in[2];
    const float* Ws_[3]    = {(const float*)d_in[3], (const float*)d_in[7],  (const float*)d_in[11]};
    const float* gs_[3]    = {(const float*)d_in[5], (const float*)d_in[9],  (const float*)d_in[13]};
    const float* betas_[3] = {(const float*)d_in[6], (const float*)d_in[10], (const float*)d_in[14]};
    const float* fcW = (const float*)d_in[15];
    const float* fcb = (const float*)d_in[16];
    float* out = (float*)d_out;

    const int N = in_sizes[0] / C_IN;
    const int E = in_sizes[1];
    const int Npad = ((N + 127) / 128) * 128;
    const int nScanBlocks = (N + 1023) / 1024;
    const int epc = (E + ECHUNK - 1) / ECHUNK;
    const int bpc = ((epc + 3) / 4 + 255) / 256;
    const int gemm_rows = Npad / 128;
    const int chunk = (gemm_rows + 7) / 8;

    char* ws = (char*)d_ws;
    size_t o = 0;
    auto alloc = [&](size_t bytes) { size_t p = o; o = (o + bytes + 511) & ~(size_t)511; return p; };
    float* norm_src = (float*)(ws + alloc((size_t)N * 4));
    int* cnt_in     = (int*)(ws + alloc((size_t)N * 4));
    float* norm_dst = (float*)(ws + alloc((size_t)N * 4));
    int* row_ptr    = (int*)(ws + alloc((size_t)(N + 1) * 4));
    int* block_sums = (int*)(ws + alloc((size_t)(nScanBlocks + 1) * 4));
    int* csr_src    = (int*)(ws + alloc((size_t)E * 4));
    unsigned short* rank = (unsigned short*)(ws + alloc((size_t)E * 2));
    unsigned int* partpk = (unsigned int*)(ws + alloc((size_t)ECHUNK * NPAD2 * 4));
    unsigned short* chunk_off = (unsigned short*)(ws + alloc((size_t)ECHUNK * NPAD2 * 2));
    float* statsPart= (float*)(ws + alloc((size_t)gemm_rows * 2 * 256 * 4));
    float* part2    = (float*)(ws + alloc(8 * 512 * 4));
    float* ss       = (float*)(ws + alloc(512 * 4));
    unsigned short* Wt[3];
    Wt[0] = (unsigned short*)(ws + alloc(256 * 256 * 2));
    Wt[1] = (unsigned short*)(ws + alloc(256 * 256 * 2));
    Wt[2] = (unsigned short*)(ws + alloc(256 * 256 * 2));
    unsigned short* Wtfc = (unsigned short*)(ws + alloc(128 * 256 * 2));
    unsigned short* hbuf   = (unsigned short*)(ws + alloc((size_t)Npad * 256 * 2));
    unsigned short* aggbuf = (unsigned short*)(ws + alloc((size_t)Npad * 256 * 2));
    unsigned short* ybuf   = (unsigned short*)(ws + alloc((size_t)Npad * 256 * 2));
    (void)ws_size; (void)n_in; (void)out_size;

    // graph prep: no global atomics anywhere
    hist_pass<<<NCHUNK * ECHUNK, 256, 0, stream>>>(src, dst, partpk, rank, E, epc);
    reduce_scan<<<(N + 255) / 256, 256, 0, stream>>>(partpk, chunk_off, norm_src, cnt_in, N);
    scan_blocks<<<nScanBlocks, 256, 0, stream>>>(cnt_in, norm_src, norm_dst, row_ptr, block_sums, N);
    scan_add<<<(N + 255) / 256, 256, 0, stream>>>(row_ptr, block_sums, N, E, nScanBlocks);
    csr_scatter<<<ECHUNK * bpc, 256, 0, stream>>>(src, dst, rank, row_ptr, chunk_off, csr_src, E, epc, bpc);

    cvt_w_all<<<(3 * 65536 + 128 * 256 + 255) / 256, 256, 0, stream>>>(
        Ws_[0], Ws_[1], Ws_[2], fcW, Wt[0], Wt[1], Wt[2], Wtfc);

    int nb64 = (N * 64 + 255) / 256;
    cvt_x<<<nb64, 256, 0, stream>>>(x, norm_src, hbuf, N);

    int agg_blocks = (N + 3) / 4;
    float invN = 1.0f / (float)N;

    for (int layer = 0; layer < 3; ++layer) {
        if (layer == 0)
            aggregate_bf16<<<agg_blocks, 256, 0, stream>>>(hbuf, csr_src, row_ptr, norm_dst, aggbuf, N);
        else
            aggregate_bn_fused<<<agg_blocks, 256, 0, stream>>>(ybuf, ss, norm_src, csr_src, row_ptr,
                                                               norm_dst, aggbuf, N);
        gemm_mfma<<<dim3(gemm_rows, 2), 256, 0, stream>>>(aggbuf, Wt[layer], nullptr, nullptr, ybuf,
                                                          statsPart, N, C_HID);
        bn_reduce<<<8, 512, 0, stream>>>(statsPart, part2, gemm_rows, chunk);
        bn_params<<<1, 256, 0, stream>>>(part2, gs_[layer], betas_[layer], ss, invN);
    }
    // last layer BN applied standalone (no next aggregate to fuse into)
    bn_relu_cvt<<<nb64, 256, 0, stream>>>(ybuf, ss, hbuf, N);
    gemm_mfma<<<dim3(gemm_rows, 1), 256, 0, stream>>>(hbuf, Wtfc, fcb, out, nullptr, nullptr, N, C_OUT);
}